// Round 17
// baseline (209.975 us; speedup 1.0000x reference)
//
#include <hip/hip_runtime.h>
#include <math.h>

static constexpr int KNN = 40;

__device__ __forceinline__ float lrelu_f(float v){ return v >= 0.f ? v : 0.5f*v; }

typedef _Float16 half8 __attribute__((ext_vector_type(8)));
typedef float    f32x4 __attribute__((ext_vector_type(4)));

__device__ __forceinline__ void gload16(const void* g, void* l){
    __builtin_amdgcn_global_load_lds((const __attribute__((address_space(1))) void*)g,
                                     (__attribute__((address_space(3))) void*)l, 16, 0, 0);
}

// ---- fp32 padded-weight offsets (floats) ----
#define PAD_OFF_GWS   0
#define PAD_OFF_GWH   192
#define PAD_OFF_N1W2  576
#define PAD_OFF_N2W3  1600
#define PAD_OFF_N3W3  3616
#define PAD_TOTAL     5632

// ---- fp16 transposed weight offsets (halves): WT[n][k], n padded to 128 ----
#define T_N2W0  0
#define T_N2W1  8192
#define T_N2W2  24576
#define T_N3W0  40960
#define T_N3W1  53248
#define T_N3W2  69632
#define T_TOTAL 86016

__global__ void pad_all(const float* gWs,const float* gWh,const float* n1W2,
                        const float* n2W3,const float* n3W3,
                        const float* n2W0,const float* n2W1,const float* n2W2,
                        const float* n3W0,const float* n3W1,const float* n3W2,
                        float* __restrict__ wp, _Float16* __restrict__ wt)
{
    int i = blockIdx.x*blockDim.x + threadIdx.x;
    if (i < PAD_TOTAL) {
        const float* src; int cols, sh, off;
        if      (i < PAD_OFF_GWH)  { src=gWs;  cols=8;  sh=4; off=PAD_OFF_GWS;  }
        else if (i < PAD_OFF_N1W2) { src=gWh;  cols=22; sh=5; off=PAD_OFF_GWH;  }
        else if (i < PAD_OFF_N2W3) { src=n1W2; cols=12; sh=4; off=PAD_OFF_N1W2; }
        else if (i < PAD_OFF_N3W3) { src=n2W3; cols=6;  sh=4; off=PAD_OFF_N2W3; }
        else                       { src=n3W3; cols=6;  sh=4; off=PAD_OFF_N3W3; }
        int li = i - off;
        int r = li >> sh, c = li & ((1<<sh)-1);
        wp[i] = (c < cols) ? src[r*cols + c] : 0.f;
        return;
    }
    int j = i - PAD_TOTAL;
    if (j >= T_TOTAL) return;
    const float* src; int KP, K, off;
    if      (j < T_N2W1) { src=n2W0; KP=64;  K=64;  off=T_N2W0; }
    else if (j < T_N2W2) { src=n2W1; KP=128; K=126; off=T_N2W1; }
    else if (j < T_N3W0) { src=n2W2; KP=128; K=126; off=T_N2W2; }
    else if (j < T_N3W1) { src=n3W0; KP=96;  K=82;  off=T_N3W0; }
    else if (j < T_N3W2) { src=n3W1; KP=128; K=126; off=T_N3W1; }
    else                 { src=n3W2; KP=128; K=126; off=T_N3W2; }
    int li = j - off;
    int n = li / KP, k = li - n*KP;
    float v = (n < 126 && k < K) ? src[k*126 + n] : 0.f;
    wt[j] = (_Float16)v;
}

// ---- lin8: wave owns 8 output cols -> wave-uniform W addresses (64 rows) ----
template<int K, int NOUT, int WPITCH, bool RELU, int NTH>
__device__ __forceinline__
void lin8(const float* __restrict__ Xs, int xpitch,
          const float* __restrict__ W, const float* __restrict__ Bv,
          float* __restrict__ Y, int ypitch, int tid)
{
    constexpr int NP  = ((NOUT+7)/8)*8;
    constexpr int NCG = NP/8;
    constexpr int NW  = NTH/64;
    const int lane = tid & 63;
    for (int g0 = tid >> 6; g0 < NCG; g0 += NW) {
        const int cg = __builtin_amdgcn_readfirstlane(g0);
        float acc[8];
        #pragma unroll
        for (int j=0;j<8;++j){ int c=cg*8+j; acc[j] = (c < NOUT) ? Bv[c] : 0.f; }
        const float* xrow = &Xs[(long)lane*xpitch];
        const float* wp = &W[cg*8];
        #pragma unroll 4
        for (int k=0;k<K;++k){
            const float xv = xrow[k];
            const float4* w4 = reinterpret_cast<const float4*>(wp + (long)k*WPITCH);
            float4 a = w4[0], b = w4[1];
            acc[0]=fmaf(xv,a.x,acc[0]); acc[1]=fmaf(xv,a.y,acc[1]);
            acc[2]=fmaf(xv,a.z,acc[2]); acc[3]=fmaf(xv,a.w,acc[3]);
            acc[4]=fmaf(xv,b.x,acc[4]); acc[5]=fmaf(xv,b.y,acc[5]);
            acc[6]=fmaf(xv,b.z,acc[6]); acc[7]=fmaf(xv,b.w,acc[7]);
        }
        #pragma unroll
        for (int j=0;j<8;++j){
            int c = cg*8 + j;
            if (c < NOUT){ float v = acc[j]; if (RELU) v = lrelu_f(v); Y[(long)lane*ypitch + c] = v; }
        }
    }
    __syncthreads();
}

// ---- lin4_dual_32: 32 rows, dual input, 512 threads, NOUT=64 ----
// wave w owns cols [8w,8w+8); lane = row + 32*h, h selects 4-col half.
template<int K, int WPITCH>
__device__ __forceinline__
void lin4_dual_32(const float* __restrict__ Xs, int xp, const float* __restrict__ X2s, int xp2,
                  const float* __restrict__ W, const float* __restrict__ Bv, const float* __restrict__ W2,
                  float* __restrict__ Y, int ypitch, int tid)
{
    const int lane = tid & 63;
    const int w    = tid >> 6;           // 0..7
    const int r    = lane & 31;
    const int h    = lane >> 5;          // 0..1
    const int c0   = w*8 + h*4;
    float acc[4];
    #pragma unroll
    for (int j=0;j<4;++j) acc[j] = Bv[c0+j];
    {
        const float* xrow = &Xs[(long)r*xp];
        const float* wp = &W[c0];
        #pragma unroll 4
        for (int k=0;k<K;++k){
            const float xv = xrow[k];
            float4 a = *reinterpret_cast<const float4*>(wp + (long)k*WPITCH);
            acc[0]=fmaf(xv,a.x,acc[0]); acc[1]=fmaf(xv,a.y,acc[1]);
            acc[2]=fmaf(xv,a.z,acc[2]); acc[3]=fmaf(xv,a.w,acc[3]);
        }
    }
    {
        const float* xrow = &X2s[(long)r*xp2];
        const float* wp = &W2[c0];
        #pragma unroll 4
        for (int k=0;k<K;++k){
            const float xv = xrow[k];
            float4 a = *reinterpret_cast<const float4*>(wp + (long)k*WPITCH);
            acc[0]=fmaf(xv,a.x,acc[0]); acc[1]=fmaf(xv,a.y,acc[1]);
            acc[2]=fmaf(xv,a.z,acc[2]); acc[3]=fmaf(xv,a.w,acc[3]);
        }
    }
    #pragma unroll
    for (int j=0;j<4;++j) Y[(long)r*ypitch + c0 + j] = acc[j];
    __syncthreads();
}

// ---------------- F1: nn1 encoder + gWs + gWh + SA/SB build (512 thr) ----------------
__global__ __launch_bounds__(512)
void f1_encoder(const float* __restrict__ x0, const float* __restrict__ wp,
                const float* n1W0,const float* n1b0,const float* n1W1,const float* n1b1,
                const float* n1b2, const float* gbs, const float* gbh,
                float* __restrict__ x12g,
                _Float16* __restrict__ SA16, _Float16* __restrict__ SB16 /*pitch 40*/,
                float* __restrict__ hg /*pitch 32*/)
{
    __shared__ float A1[64*65], A2[64*65], Ss[64*9];
    const int tid = threadIdx.x;
    const long row0 = (long)blockIdx.x*64;
    lin8<12,64,64,true,512>(x0+row0*12,12, n1W0, n1b0, A1,65, tid);
    lin8<64,64,64,true,512>(A1,65, n1W1, n1b1, A2,65, tid);
    lin8<64,12,16,true,512>(A2,65, wp+PAD_OFF_N1W2, n1b2, A1,13, tid);
    for (int i=tid;i<64*12;i+=512){ int r=i/12,c=i-r*12; x12g[(row0+r)*12+c]=A1[r*13+c]; }
    lin8<12,8,16,false,512>(A1,13, wp+PAD_OFF_GWS, gbs, Ss,9, tid);
    lin8<12,22,32,false,512>(A1,13, wp+PAD_OFF_GWH, gbh, hg+row0*32,32, tid);
    if (tid < 64) {
        const long node = row0 + tid;
        float sv[8]; float nq = 0.f;
        #pragma unroll
        for (int k=0;k<8;++k){ float v=Ss[tid*9+k]; sv[k]=v; nq=fmaf(v,v,nq); }
        _Float16 ch[8], clo[8];
        #pragma unroll
        for (int k=0;k<8;++k){ ch[k]=(_Float16)sv[k]; clo[k]=(_Float16)(sv[k]-(float)ch[k]); }
        _Float16 nh = (_Float16)nq, nl = (_Float16)(nq-(float)nh);
        const _Float16 one = (_Float16)1.f, zero = (_Float16)0.f;
        half8 a0,a1,a2,b0,b2;
        #pragma unroll
        for (int k=0;k<8;++k){
            a0[k]=ch[k]; a1[k]=clo[k]; a2[k]=ch[k];
            b0[k]=(_Float16)(-2.f*(float)ch[k]);
            b2[k]=(_Float16)(-2.f*(float)clo[k]);
        }
        half8 a3 = {nh, nl, one, one, zero, zero, zero, zero};
        half8 b3 = {one, one, nh, nl, zero, zero, zero, zero};
        half8* ap = (half8*)&SA16[(size_t)node*32];
        ap[0]=a0; ap[1]=a1; ap[2]=a2; ap[3]=a3;
        half8* bp = (half8*)&SB16[(size_t)node*40];
        bp[0]=b0; bp[1]=b0; bp[2]=b2; bp[3]=b3;
        bp[4]=half8{zero,zero,zero,zero,zero,zero,zero,zero};
    }
}

// ---------------- kNN scan (unchanged) ----------------
template<int C>
__device__ __forceinline__ unsigned dpp_umin(unsigned x){
    unsigned y = (unsigned)__builtin_amdgcn_update_dpp((int)x, (int)x, C, 0xf, 0xf, false);
    return x < y ? x : y;
}
__device__ __forceinline__ unsigned wave_umin64(unsigned x){
    x = dpp_umin<0x111>(x);
    x = dpp_umin<0x112>(x);
    x = dpp_umin<0x114>(x);
    x = dpp_umin<0x118>(x);
    x = dpp_umin<0x142>(x);
    x = dpp_umin<0x143>(x);
    return x;
}
__device__ __forceinline__ unsigned med3_u32(unsigned a, unsigned b, unsigned c){
    unsigned d;
    asm("v_med3_u32 %0, %1, %2, %3" : "=v"(d) : "v"(a), "v"(b), "v"(c));
    return d;
}

__global__ __launch_bounds__(512)
void knn_scan(const _Float16* __restrict__ SA, const _Float16* __restrict__ SB,
              unsigned* __restrict__ part, int N)
{
    __shared__ __align__(16) _Float16 SBl[2][256*40];
    const int tid  = threadIdx.x;
    const int lane = tid & 63;
    const int w    = tid >> 6;
    const int g    = w >> 2, qt = w & 3;
    const int col  = lane & 15, kg = lane >> 4;
    const int qg   = blockIdx.x >> 1, half = blockIdx.x & 1;
    const int qb   = qg*32 + g*16;
    const int qtile = qb >> 8;
    const int rhs0  = (qb & 255) + kg*4;
    const int T0 = half*32;

    half8 afrag = *(const half8*)&SA[(size_t)(qb + col)*32 + kg*8];
    unsigned s0[4], s1[4];
    #pragma unroll
    for (int r=0;r<4;++r){ s0[r]=0xFFFFFFFFu; s1[r]=0xFFFFFFFFu; }

    {
        const char* gp = (const char*)(SB + (size_t)T0*256*40);
        gload16(gp + (size_t)tid*16,        &SBl[0][(size_t)tid*8]);
        gload16(gp + (size_t)(tid+512)*16,  &SBl[0][(size_t)(tid+512)*8]);
        if (tid < 256) gload16(gp + (size_t)(tid+1024)*16, &SBl[0][(size_t)(tid+1024)*8]);
    }
    __syncthreads();
    #pragma unroll 1
    for (int t = T0; t < T0+32; ++t) {
        const int cur = t & 1;
        if (t+1 < T0+32) {
            const char* gp = (const char*)(SB + (size_t)(t+1)*256*40);
            _Float16* lp = SBl[cur^1];
            gload16(gp + (size_t)tid*16,        &lp[(size_t)tid*8]);
            gload16(gp + (size_t)(tid+512)*16,  &lp[(size_t)(tid+512)*8]);
            if (tid < 256) gload16(gp + (size_t)(tid+1024)*16, &lp[(size_t)(tid+1024)*8]);
        }
        const _Float16* tb = SBl[cur];
        if (t != qtile) {
            #pragma unroll
            for (int c3=0;c3<4;++c3){
                const int cl_ = (qt*4+c3)*16 + col;
                half8 b = *(const half8*)&tb[cl_*40 + kg*8];
                f32x4 acc = {0.f,0.f,0.f,0.f};
                acc = __builtin_amdgcn_mfma_f32_16x16x32_f16(afrag, b, acc, 0, 0, 0);
                const unsigned ib = (unsigned)((t<<8)|cl_);
                #pragma unroll
                for (int r=0;r<4;++r){
                    float d2 = fmaxf(acc[r], 0.f);
                    unsigned key = (__float_as_uint(d2) & 0xFFFFC000u) | ib;
                    unsigned lo = s0[r] < key ? s0[r] : key;
                    s1[r] = med3_u32(s0[r], s1[r], key);
                    s0[r] = lo;
                }
            }
        } else {
            #pragma unroll
            for (int c3=0;c3<4;++c3){
                const int cl_ = (qt*4+c3)*16 + col;
                half8 b = *(const half8*)&tb[cl_*40 + kg*8];
                f32x4 acc = {0.f,0.f,0.f,0.f};
                acc = __builtin_amdgcn_mfma_f32_16x16x32_f16(afrag, b, acc, 0, 0, 0);
                const unsigned ib = (unsigned)((t<<8)|cl_);
                #pragma unroll
                for (int r=0;r<4;++r){
                    float d2 = fmaxf(acc[r], 0.f);
                    unsigned key = (__float_as_uint(d2) & 0xFFFFC000u) | ib;
                    if (cl_ == rhs0 + r) key = 0xFFFFFFFFu;
                    unsigned lo = s0[r] < key ? s0[r] : key;
                    s1[r] = med3_u32(s0[r], s1[r], key);
                    s0[r] = lo;
                }
            }
        }
        __syncthreads();
    }

    #pragma unroll
    for (int r=0;r<4;++r){
        const long q = (long)qg*32 + g*16 + kg*4 + r;
        unsigned* pp = &part[((size_t)q*2 + half)*128 + qt*32 + col*2];
        pp[0] = s0[r]; pp[1] = s1[r];
    }
}

// ---------------- kNN merge ----------------
__global__ __launch_bounds__(512)
void knn_merge(const unsigned* __restrict__ part,
               int* __restrict__ idx_out, float* __restrict__ w_out)
{
    const int lane = threadIdx.x & 63, w = threadIdx.x >> 6;
    const long q = (long)blockIdx.x*8 + w;
    const uint4 kk = *reinterpret_cast<const uint4*>(&part[(size_t)q*256 + lane*4]);
    unsigned k0=kk.x, k1=kk.y, k2=kk.z, k3=kk.w;
    unsigned saved = 0;
    #pragma unroll 1
    for (int p=0;p<KNN;++p){
        unsigned a = k0 < k1 ? k0 : k1;
        unsigned b = k2 < k3 ? k2 : k3;
        unsigned lmin = a < b ? a : b;
        unsigned red = wave_umin64(lmin);
        unsigned gm = (unsigned)__builtin_amdgcn_readlane((int)red, 63);
        unsigned long long bal = __ballot(lmin == gm);
        int owner = __ffsll((long long)bal) - 1;
        if (lane == owner){
            if      (k0 == gm) k0 = 0xFFFFFFFFu;
            else if (k1 == gm) k1 = 0xFFFFFFFFu;
            else if (k2 == gm) k2 = 0xFFFFFFFFu;
            else               k3 = 0xFFFFFFFFu;
        }
        if (lane == p) saved = gm;
    }
    if (lane < KNN){
        idx_out[q*KNN + lane] = (int)(saved & 16383u);
        const float d2 = __uint_as_float(saved & 0xFFFFC000u);
        w_out[q*KNN + lane] = expf(-10.f*d2);
    }
}

// ---------------- F2: GravNet aggregate + lin 56->64 (512 thr) ----------------
__global__ __launch_bounds__(512)
void f2_agg(const float* __restrict__ hg /*pitch 32*/, const int* __restrict__ idx,
            const float* __restrict__ wgt, const float* __restrict__ x12g,
            const float* gWo, const float* gbo, float* __restrict__ xg)
{
    __shared__ int   IDs[64*40];
    __shared__ float Wt[64*40];
    __shared__ float AGG[64*57];
    const int tid = threadIdx.x;
    const long row0 = (long)blockIdx.x*64;
    for (int i=tid;i<64*40;i+=512){ int r=i/40,k=i-r*40;
        IDs[i]=idx[(row0+r)*40+k]; Wt[i]=wgt[(row0+r)*40+k]; }
    for (int i=tid;i<64*12;i+=512){ int r=i/12,c=i-r*12; AGG[r*57+44+c]=x12g[(row0+r)*12+c]; }
    __syncthreads();
    {
        const int r = tid & 63, g = tid >> 6;
        const int f0 = g*4;
        const int nf = (f0 < 22) ? ((22-f0) < 4 ? (22-f0) : 4) : 0;
        float sm[4], mx[4];
        #pragma unroll
        for (int u=0;u<4;++u){ sm[u]=0.f; mx[u]=-INFINITY; }
        if (nf > 0) {
            #pragma unroll 1
            for (int k=0;k<40;++k){
                int j = IDs[r*40+k]; float wv = Wt[r*40+k];
                float4 h0 = *reinterpret_cast<const float4*>(&hg[(long)j*32 + f0]);
                float hv[4] = {h0.x,h0.y,h0.z,h0.w};
                #pragma unroll
                for (int u=0;u<4;++u){ float m = hv[u]*wv; sm[u]+=m; mx[u]=fmaxf(mx[u],m); }
            }
            #pragma unroll
            for (int u=0;u<4;++u) if (u<nf){ AGG[r*57+f0+u]=sm[u]*(1.f/40.f); AGG[r*57+22+f0+u]=mx[u]; }
        }
    }
    __syncthreads();
    lin8<56,64,64,false,512>(AGG,57, gWo, gbo, xg+row0*64,64, tid);
}

// ---------------- F345: GraphConv + nn2 + nn3 fused (32 rows, 512 thr) ----------------
// mfma_layer32: 8 waves; wave wid: m = wid&1 (row-tile), nb = wid>>1; col-tiles nb, nb+4.
template<int KP>
__device__ __forceinline__
void mfma_layer32(const _Float16* __restrict__ Xl, const _Float16* __restrict__ WTg,
                  _Float16* __restrict__ Wl,
                  const float* __restrict__ Bv, _Float16* __restrict__ Yl, int tid)
{
    {
        const half8* src = reinterpret_cast<const half8*>(WTg);
        half8* dst = reinterpret_cast<half8*>(Wl);
        constexpr int CHUNKS = 128*KP/8;
        #pragma unroll
        for (int i = tid; i < CHUNKS; i += 512) dst[i] = src[i];
    }
    __syncthreads();
    const int lane = tid & 63;
    const int wid  = __builtin_amdgcn_readfirstlane(tid >> 6);
    const int m   = wid & 1;
    const int nb  = wid >> 1;
    const int c15 = lane & 15;
    const int kg  = lane >> 4;
    f32x4 acc0 = {0.f,0.f,0.f,0.f};
    f32x4 acc1 = {0.f,0.f,0.f,0.f};
    const _Float16* xb = &Xl[(m*16 + c15)*136];
    const _Float16* w0 = &Wl[(nb*16 + c15)*KP];
    const _Float16* w1 = &Wl[((nb+4)*16 + c15)*KP];
    #pragma unroll
    for (int ks = 0; ks < KP/32; ++ks) {
        const int kb = kg*8 + ks*32;
        half8 a  = *reinterpret_cast<const half8*>(&xb[kb]);
        half8 b0 = *reinterpret_cast<const half8*>(&w0[kb]);
        half8 b1 = *reinterpret_cast<const half8*>(&w1[kb]);
        acc0 = __builtin_amdgcn_mfma_f32_16x16x32_f16(a, b0, acc0, 0, 0, 0);
        acc1 = __builtin_amdgcn_mfma_f32_16x16x32_f16(a, b1, acc1, 0, 0, 0);
    }
    const int drow = m*16 + kg*4;
    const int c0 = nb*16 + c15;
    const int c1 = (nb+4)*16 + c15;
    #pragma unroll
    for (int r = 0; r < 4; ++r) {
        float v0 = (c0 < 126) ? lrelu_f(acc0[r] + Bv[c0]) : 0.f;
        float v1 = (c1 < 126) ? lrelu_f(acc1[r] + Bv[c1]) : 0.f;
        Yl[(drow+r)*136 + c0] = (_Float16)v0;
        Yl[(drow+r)*136 + c1] = (_Float16)v1;
    }
    __syncthreads();
}

__device__ __forceinline__
void lin_out6h32(const _Float16* __restrict__ Xs, const float* __restrict__ Wp,
                 float* __restrict__ Wl6, const float* __restrict__ Bv,
                 float* __restrict__ Y, int ypitch, int tid)
{
    for (int i = tid; i < 126*8; i += 512) {
        int k = i >> 3, c = i & 7;
        Wl6[i] = Wp[k*16 + c];
    }
    __syncthreads();
    if (tid < 32*6) {
        const int r = tid / 6, c = tid - r*6;
        float acc = Bv[c];
        const _Float16* xrow = &Xs[r*136];
        #pragma unroll 4
        for (int k=0;k<126;++k) acc = fmaf((float)xrow[k], Wl6[k*8+c], acc);
        Y[(long)r*ypitch + c] = lrelu_f(acc);
    }
    __syncthreads();
}

__global__ __launch_bounds__(512)
void f345(const float* __restrict__ xgin, const int* __restrict__ idx,
          const float* __restrict__ wgt,
          const float* c2Wrel, const float* c2brel, const float* c2Wroot,
          const float* __restrict__ x0,
          const float* __restrict__ wp, const _Float16* __restrict__ wt,
          const float* A_b0,const float* A_b1,const float* A_b2,const float* A_b3,
          const float* B_b0,const float* B_b1,const float* B_b2,const float* B_b3,
          float* __restrict__ outIds, float* __restrict__ outP4)
{
    __shared__ float XCs[32*65];                      // persistent xc (fp32), 8320 B
    __shared__ __align__(16) char uni[50944];         // phase-union scratch
    // f3 view
    int*   IDs = (int*)uni;                           // 5120 B
    float* Wt  = (float*)(uni+5120);                  // 5120 B
    float* NB  = (float*)(uni+10240);                 // 8320 B
    float* XGs = (float*)(uni+18560);                 // 8320 B
    // f45 view
    _Float16* bufA = (_Float16*)uni;                  // 8704 B
    _Float16* bufB = (_Float16*)(uni+8704);           // 8704 B
    _Float16* Wl   = (_Float16*)(uni+17408);          // 32768 B
    float*    IDS6 = (float*)(uni+50176);             // 768 B

    const int tid = threadIdx.x;
    const long row0 = (long)blockIdx.x*32;
    // ---- f3: gather + dual linear -> XCs ----
    for (int i=tid;i<32*40;i+=512){ int r=i/40,k=i-r*40;
        IDs[i]=idx[(row0+r)*40+k]; Wt[i]=wgt[(row0+r)*40+k]; }
    for (int i=tid;i<32*64;i+=512){ int r=i>>6,c=i&63; XGs[r*65+c]=xgin[(row0+r)*64+c]; }
    __syncthreads();
    {
        const int r = tid & 31, g = tid >> 5;   // g in 0..15, cols [4g,4g+4)
        float acc[4] = {0.f,0.f,0.f,0.f};
        #pragma unroll 1
        for (int k=0;k<40;++k){
            int j = IDs[r*40+k]; float wv = Wt[r*40+k];
            float4 v = *reinterpret_cast<const float4*>(&xgin[(long)j*64 + g*4]);
            acc[0]=fmaf(v.x,wv,acc[0]); acc[1]=fmaf(v.y,wv,acc[1]);
            acc[2]=fmaf(v.z,wv,acc[2]); acc[3]=fmaf(v.w,wv,acc[3]);
        }
        __syncthreads();
        #pragma unroll
        for (int j=0;j<4;++j) NB[r*65 + g*4 + j] = acc[j];
    }
    __syncthreads();
    lin4_dual_32<64,64>(NB,65, XGs,65, c2Wrel,c2brel,c2Wroot, XCs,65, tid);
    // ---- f45: nn2 ----
    for (int i=tid;i<32*64;i+=512){ int r=i>>6,c=i&63;
        bufA[r*136+c] = (_Float16)XCs[r*65+c]; }
    __syncthreads();
    mfma_layer32<64>(bufA, wt+T_N2W0, Wl, A_b0, bufB, tid);
    mfma_layer32<128>(bufB, wt+T_N2W1, Wl, A_b1, bufA, tid);
    mfma_layer32<128>(bufA, wt+T_N2W2, Wl, A_b2, bufB, tid);
    lin_out6h32(bufB, wp+PAD_OFF_N2W3, (float*)Wl, A_b3, IDS6, 6, tid);
    for (int i=tid;i<32*6;i+=512){ int r=i/6,c=i-r*6; outIds[(row0+r)*6+c]=IDS6[i]; }
    // ---- concat [xc, ids, x0] -> bufA (96 cols) ----
    for (int i=tid;i<32*96;i+=512){
        int r=i/96, c=i-r*96;
        float v;
        if (c < 64)      v = XCs[r*65 + c];
        else if (c < 70) v = IDS6[r*6 + (c-64)];
        else if (c < 82) v = x0[(row0+r)*12 + (c-70)];
        else             v = 0.f;
        bufA[r*136+c] = (_Float16)v;
    }
    __syncthreads();
    // ---- nn3 ----
    mfma_layer32<96>(bufA, wt+T_N3W0, Wl, B_b0, bufB, tid);
    mfma_layer32<128>(bufB, wt+T_N3W1, Wl, B_b1, bufA, tid);
    mfma_layer32<128>(bufA, wt+T_N3W2, Wl, B_b2, bufB, tid);
    lin_out6h32(bufB, wp+PAD_OFF_N3W3, (float*)Wl, B_b3, outP4+row0*6, 6, tid);
}

// ---------------- passthrough outputs ----------------
__global__ void copyout_kernel(const int* __restrict__ gid, const float* __restrict__ gy,
                               const int* __restrict__ cid, const float* __restrict__ cy,
                               float* __restrict__ out, int N)
{
    long i = (long)blockIdx.x*blockDim.x + threadIdx.x;
    long n = N;
    if (i < n)            out[12*n + i]         = (float)gid[i];
    else if (i < 7*n)     out[13*n + (i - n)]   = gy[i - n];
    else if (i < 8*n)     out[19*n + (i - 7*n)] = (float)cid[i - 7*n];
    else if (i < 14*n)    out[20*n + (i - 8*n)] = cy[i - 8*n];
}

extern "C" void kernel_launch(void* const* d_in, const int* in_sizes, int n_in,
                              void* d_out, int out_size, void* d_ws, size_t ws_size,
                              hipStream_t stream)
{
    const float* x0     = (const float*)d_in[0];
    const float* ygen   = (const float*)d_in[1];
    const float* ycand  = (const float*)d_in[2];
    const int*   ygenid = (const int*)d_in[3];
    const int*   ycandid= (const int*)d_in[4];
    const float* n1W0=(const float*)d_in[5],  *n1b0=(const float*)d_in[6];
    const float* n1W1=(const float*)d_in[7],  *n1b1=(const float*)d_in[8];
    const float* n1W2=(const float*)d_in[9],  *n1b2=(const float*)d_in[10];
    const float* gWs =(const float*)d_in[11], *gbs =(const float*)d_in[12];
    const float* gWh =(const float*)d_in[13], *gbh =(const float*)d_in[14];
    const float* gWo =(const float*)d_in[15], *gbo =(const float*)d_in[16];
    const float* c2Wrel=(const float*)d_in[17], *c2brel=(const float*)d_in[18];
    const float* c2Wroot=(const float*)d_in[19];
    const float* n2W0=(const float*)d_in[20], *n2b0=(const float*)d_in[21];
    const float* n2W1=(const float*)d_in[22], *n2b1=(const float*)d_in[23];
    const float* n2W2=(const float*)d_in[24], *n2b2=(const float*)d_in[25];
    const float* n2W3=(const float*)d_in[26], *n2b3=(const float*)d_in[27];
    const float* n3W0=(const float*)d_in[28], *n3b0=(const float*)d_in[29];
    const float* n3W1=(const float*)d_in[30], *n3b1=(const float*)d_in[31];
    const float* n3W2=(const float*)d_in[32], *n3b2=(const float*)d_in[33];
    const float* n3W3=(const float*)d_in[34], *n3b3=(const float*)d_in[35];

    const int N = in_sizes[0] / 12;      // 16384
    float* ws = (float*)d_ws;
    size_t off = 0;
    auto alloc = [&](size_t cnt){ float* p = ws + off; off += cnt; return p; };
    float* padw = alloc(PAD_TOTAL);
    _Float16* wt16 = (_Float16*)alloc((T_TOTAL+1)/2 + 8);
    float* x12  = alloc((size_t)N*12);
    _Float16* SA16 = (_Float16*)alloc((size_t)N*16);
    _Float16* SB16 = (_Float16*)alloc((size_t)N*20);
    float* h    = alloc((size_t)N*32);
    unsigned* part = (unsigned*)alloc((size_t)N*256);
    int*   idxb = (int*)alloc((size_t)N*KNN);
    float* wb   = alloc((size_t)N*KNN);
    float* xg   = alloc((size_t)N*64);
    (void)ws_size; (void)n_in; (void)out_size;

    float* outF = (float*)d_out;
    const int GB = N / 64;               // 256 blocks

    pad_all<<<(PAD_TOTAL+T_TOTAL+255)/256,256,0,stream>>>(gWs,gWh,n1W2,n2W3,n3W3,
                                                          n2W0,n2W1,n2W2,n3W0,n3W1,n3W2,
                                                          padw, wt16);
    f1_encoder<<<GB,512,0,stream>>>(x0, padw, n1W0,n1b0, n1W1,n1b1, n1b2,
                                    gbs, gbh, x12, SA16, SB16, h);
    knn_scan<<<(N/32)*2, 512, 0, stream>>>(SA16, SB16, part, N);
    knn_merge<<<N/8, 512, 0, stream>>>(part, idxb, wb);
    f2_agg<<<GB,512,0,stream>>>(h, idxb, wb, x12, gWo, gbo, xg);
    f345<<<N/32,512,0,stream>>>(xg, idxb, wb, c2Wrel, c2brel, c2Wroot, x0, padw, wt16,
                                n2b0,n2b1,n2b2,n2b3, n3b0,n3b1,n3b2,n3b3,
                                outF, outF + (size_t)N*6);
    copyout_kernel<<<(14*N+255)/256,256,0,stream>>>(ygenid, ygen, ycandid, ycand, outF, N);
}

// Round 18
// 201.808 us; speedup vs baseline: 1.0405x; 1.0405x over previous
//
#include <hip/hip_runtime.h>
#include <math.h>

static constexpr int KNN = 40;

__device__ __forceinline__ float lrelu_f(float v){ return v >= 0.f ? v : 0.5f*v; }

typedef _Float16 half8 __attribute__((ext_vector_type(8)));
typedef float    f32x4 __attribute__((ext_vector_type(4)));

__device__ __forceinline__ void gload16(const void* g, void* l){
    __builtin_amdgcn_global_load_lds((const __attribute__((address_space(1))) void*)g,
                                     (__attribute__((address_space(3))) void*)l, 16, 0, 0);
}

// ---- fp32 padded-weight offsets (floats) ----
#define PAD_OFF_GWS   0
#define PAD_OFF_GWH   192
#define PAD_OFF_N1W2  576
#define PAD_OFF_N2W3  1600
#define PAD_OFF_N3W3  3616
#define PAD_TOTAL     5632

// ---- fp16 transposed weight offsets (halves): WT[n][k], n padded to 128 ----
#define T_N2W0  0
#define T_N2W1  8192
#define T_N2W2  24576
#define T_N3W0  40960
#define T_N3W1  53248
#define T_N3W2  69632
#define T_TOTAL 86016

__global__ void pad_all(const float* gWs,const float* gWh,const float* n1W2,
                        const float* n2W3,const float* n3W3,
                        const float* n2W0,const float* n2W1,const float* n2W2,
                        const float* n3W0,const float* n3W1,const float* n3W2,
                        float* __restrict__ wp, _Float16* __restrict__ wt)
{
    int i = blockIdx.x*blockDim.x + threadIdx.x;
    if (i < PAD_TOTAL) {
        const float* src; int cols, sh, off;
        if      (i < PAD_OFF_GWH)  { src=gWs;  cols=8;  sh=4; off=PAD_OFF_GWS;  }
        else if (i < PAD_OFF_N1W2) { src=gWh;  cols=22; sh=5; off=PAD_OFF_GWH;  }
        else if (i < PAD_OFF_N2W3) { src=n1W2; cols=12; sh=4; off=PAD_OFF_N1W2; }
        else if (i < PAD_OFF_N3W3) { src=n2W3; cols=6;  sh=4; off=PAD_OFF_N2W3; }
        else                       { src=n3W3; cols=6;  sh=4; off=PAD_OFF_N3W3; }
        int li = i - off;
        int r = li >> sh, c = li & ((1<<sh)-1);
        wp[i] = (c < cols) ? src[r*cols + c] : 0.f;
        return;
    }
    int j = i - PAD_TOTAL;
    if (j >= T_TOTAL) return;
    const float* src; int KP, K, off;
    if      (j < T_N2W1) { src=n2W0; KP=64;  K=64;  off=T_N2W0; }
    else if (j < T_N2W2) { src=n2W1; KP=128; K=126; off=T_N2W1; }
    else if (j < T_N3W0) { src=n2W2; KP=128; K=126; off=T_N2W2; }
    else if (j < T_N3W1) { src=n3W0; KP=96;  K=82;  off=T_N3W0; }
    else if (j < T_N3W2) { src=n3W1; KP=128; K=126; off=T_N3W1; }
    else                 { src=n3W2; KP=128; K=126; off=T_N3W2; }
    int li = j - off;
    int n = li / KP, k = li - n*KP;
    float v = (n < 126 && k < K) ? src[k*126 + n] : 0.f;
    wt[j] = (_Float16)v;
}

// ---- lin8: wave owns 8 output cols -> wave-uniform W addresses (64 rows) ----
template<int K, int NOUT, int WPITCH, bool RELU, int NTH>
__device__ __forceinline__
void lin8(const float* __restrict__ Xs, int xpitch,
          const float* __restrict__ W, const float* __restrict__ Bv,
          float* __restrict__ Y, int ypitch, int tid)
{
    constexpr int NP  = ((NOUT+7)/8)*8;
    constexpr int NCG = NP/8;
    constexpr int NW  = NTH/64;
    const int lane = tid & 63;
    for (int g0 = tid >> 6; g0 < NCG; g0 += NW) {
        const int cg = __builtin_amdgcn_readfirstlane(g0);
        float acc[8];
        #pragma unroll
        for (int j=0;j<8;++j){ int c=cg*8+j; acc[j] = (c < NOUT) ? Bv[c] : 0.f; }
        const float* xrow = &Xs[(long)lane*xpitch];
        const float* wp = &W[cg*8];
        #pragma unroll 4
        for (int k=0;k<K;++k){
            const float xv = xrow[k];
            const float4* w4 = reinterpret_cast<const float4*>(wp + (long)k*WPITCH);
            float4 a = w4[0], b = w4[1];
            acc[0]=fmaf(xv,a.x,acc[0]); acc[1]=fmaf(xv,a.y,acc[1]);
            acc[2]=fmaf(xv,a.z,acc[2]); acc[3]=fmaf(xv,a.w,acc[3]);
            acc[4]=fmaf(xv,b.x,acc[4]); acc[5]=fmaf(xv,b.y,acc[5]);
            acc[6]=fmaf(xv,b.z,acc[6]); acc[7]=fmaf(xv,b.w,acc[7]);
        }
        #pragma unroll
        for (int j=0;j<8;++j){
            int c = cg*8 + j;
            if (c < NOUT){ float v = acc[j]; if (RELU) v = lrelu_f(v); Y[(long)lane*ypitch + c] = v; }
        }
    }
    __syncthreads();
}

template<int K, int NOUT, int WPITCH, int NTH>
__device__ __forceinline__
void lin8_dual(const float* __restrict__ Xs, int xp, const float* __restrict__ X2s, int xp2,
               const float* __restrict__ W, const float* __restrict__ Bv, const float* __restrict__ W2,
               float* __restrict__ Y, int ypitch, int tid)
{
    constexpr int NP  = ((NOUT+7)/8)*8;
    constexpr int NCG = NP/8;
    constexpr int NW  = NTH/64;
    const int lane = tid & 63;
    for (int g0 = tid >> 6; g0 < NCG; g0 += NW) {
        const int cg = __builtin_amdgcn_readfirstlane(g0);
        float acc[8];
        #pragma unroll
        for (int j=0;j<8;++j){ int c=cg*8+j; acc[j] = (c < NOUT) ? Bv[c] : 0.f; }
        {
            const float* xrow = &Xs[(long)lane*xp];
            const float* wp = &W[cg*8];
            #pragma unroll 4
            for (int k=0;k<K;++k){
                const float xv = xrow[k];
                const float4* w4 = reinterpret_cast<const float4*>(wp + (long)k*WPITCH);
                float4 a = w4[0], b = w4[1];
                acc[0]=fmaf(xv,a.x,acc[0]); acc[1]=fmaf(xv,a.y,acc[1]);
                acc[2]=fmaf(xv,a.z,acc[2]); acc[3]=fmaf(xv,a.w,acc[3]);
                acc[4]=fmaf(xv,b.x,acc[4]); acc[5]=fmaf(xv,b.y,acc[5]);
                acc[6]=fmaf(xv,b.z,acc[6]); acc[7]=fmaf(xv,b.w,acc[7]);
            }
        }
        {
            const float* xrow = &X2s[(long)lane*xp2];
            const float* wp = &W2[cg*8];
            #pragma unroll 4
            for (int k=0;k<K;++k){
                const float xv = xrow[k];
                const float4* w4 = reinterpret_cast<const float4*>(wp + (long)k*WPITCH);
                float4 a = w4[0], b = w4[1];
                acc[0]=fmaf(xv,a.x,acc[0]); acc[1]=fmaf(xv,a.y,acc[1]);
                acc[2]=fmaf(xv,a.z,acc[2]); acc[3]=fmaf(xv,a.w,acc[3]);
                acc[4]=fmaf(xv,b.x,acc[4]); acc[5]=fmaf(xv,b.y,acc[5]);
                acc[6]=fmaf(xv,b.z,acc[6]); acc[7]=fmaf(xv,b.w,acc[7]);
            }
        }
        #pragma unroll
        for (int j=0;j<8;++j){
            int c = cg*8 + j;
            if (c < NOUT) Y[(long)lane*ypitch + c] = acc[j];
        }
    }
    __syncthreads();
}

// ---------------- F1: nn1 encoder + gWs + gWh + SA/SB build (512 thr) ----------------
__global__ __launch_bounds__(512)
void f1_encoder(const float* __restrict__ x0, const float* __restrict__ wp,
                const float* n1W0,const float* n1b0,const float* n1W1,const float* n1b1,
                const float* n1b2, const float* gbs, const float* gbh,
                float* __restrict__ x12g,
                _Float16* __restrict__ SA16, _Float16* __restrict__ SB16 /*pitch 40*/,
                float* __restrict__ hg /*pitch 32*/)
{
    __shared__ float A1[64*65], A2[64*65], Ss[64*9];
    const int tid = threadIdx.x;
    const long row0 = (long)blockIdx.x*64;
    lin8<12,64,64,true,512>(x0+row0*12,12, n1W0, n1b0, A1,65, tid);
    lin8<64,64,64,true,512>(A1,65, n1W1, n1b1, A2,65, tid);
    lin8<64,12,16,true,512>(A2,65, wp+PAD_OFF_N1W2, n1b2, A1,13, tid);
    for (int i=tid;i<64*12;i+=512){ int r=i/12,c=i-r*12; x12g[(row0+r)*12+c]=A1[r*13+c]; }
    lin8<12,8,16,false,512>(A1,13, wp+PAD_OFF_GWS, gbs, Ss,9, tid);
    lin8<12,22,32,false,512>(A1,13, wp+PAD_OFF_GWH, gbh, hg+row0*32,32, tid);
    if (tid < 64) {
        const long node = row0 + tid;
        float sv[8]; float nq = 0.f;
        #pragma unroll
        for (int k=0;k<8;++k){ float v=Ss[tid*9+k]; sv[k]=v; nq=fmaf(v,v,nq); }
        _Float16 ch[8], clo[8];
        #pragma unroll
        for (int k=0;k<8;++k){ ch[k]=(_Float16)sv[k]; clo[k]=(_Float16)(sv[k]-(float)ch[k]); }
        _Float16 nh = (_Float16)nq, nl = (_Float16)(nq-(float)nh);
        const _Float16 one = (_Float16)1.f, zero = (_Float16)0.f;
        half8 a0,a1,a2,b0,b2;
        #pragma unroll
        for (int k=0;k<8;++k){
            a0[k]=ch[k]; a1[k]=clo[k]; a2[k]=ch[k];
            b0[k]=(_Float16)(-2.f*(float)ch[k]);
            b2[k]=(_Float16)(-2.f*(float)clo[k]);
        }
        half8 a3 = {nh, nl, one, one, zero, zero, zero, zero};
        half8 b3 = {one, one, nh, nl, zero, zero, zero, zero};
        half8* ap = (half8*)&SA16[(size_t)node*32];
        ap[0]=a0; ap[1]=a1; ap[2]=a2; ap[3]=a3;
        half8* bp = (half8*)&SB16[(size_t)node*40];
        bp[0]=b0; bp[1]=b0; bp[2]=b2; bp[3]=b3;
        bp[4]=half8{zero,zero,zero,zero,zero,zero,zero,zero};
    }
}

// ---------------- kNN scan (R15/R16 form) ----------------
template<int C>
__device__ __forceinline__ unsigned dpp_umin(unsigned x){
    unsigned y = (unsigned)__builtin_amdgcn_update_dpp((int)x, (int)x, C, 0xf, 0xf, false);
    return x < y ? x : y;
}
__device__ __forceinline__ unsigned wave_umin64(unsigned x){
    x = dpp_umin<0x111>(x);
    x = dpp_umin<0x112>(x);
    x = dpp_umin<0x114>(x);
    x = dpp_umin<0x118>(x);
    x = dpp_umin<0x142>(x);
    x = dpp_umin<0x143>(x);
    return x;
}
__device__ __forceinline__ unsigned med3_u32(unsigned a, unsigned b, unsigned c){
    unsigned d;
    asm("v_med3_u32 %0, %1, %2, %3" : "=v"(d) : "v"(a), "v"(b), "v"(c));
    return d;
}

__global__ __launch_bounds__(512)
void knn_scan(const _Float16* __restrict__ SA, const _Float16* __restrict__ SB,
              unsigned* __restrict__ part, int N)
{
    __shared__ __align__(16) _Float16 SBl[2][256*40];
    const int tid  = threadIdx.x;
    const int lane = tid & 63;
    const int w    = tid >> 6;
    const int g    = w >> 2, qt = w & 3;
    const int col  = lane & 15, kg = lane >> 4;
    const int qg   = blockIdx.x >> 1, half = blockIdx.x & 1;
    const int qb   = qg*32 + g*16;
    const int qtile = qb >> 8;
    const int rhs0  = (qb & 255) + kg*4;
    const int T0 = half*32;

    half8 afrag = *(const half8*)&SA[(size_t)(qb + col)*32 + kg*8];
    unsigned s0[4], s1[4];
    #pragma unroll
    for (int r=0;r<4;++r){ s0[r]=0xFFFFFFFFu; s1[r]=0xFFFFFFFFu; }

    {
        const char* gp = (const char*)(SB + (size_t)T0*256*40);
        gload16(gp + (size_t)tid*16,        &SBl[0][(size_t)tid*8]);
        gload16(gp + (size_t)(tid+512)*16,  &SBl[0][(size_t)(tid+512)*8]);
        if (tid < 256) gload16(gp + (size_t)(tid+1024)*16, &SBl[0][(size_t)(tid+1024)*8]);
    }
    __syncthreads();
    #pragma unroll 1
    for (int t = T0; t < T0+32; ++t) {
        const int cur = t & 1;
        if (t+1 < T0+32) {
            const char* gp = (const char*)(SB + (size_t)(t+1)*256*40);
            _Float16* lp = SBl[cur^1];
            gload16(gp + (size_t)tid*16,        &lp[(size_t)tid*8]);
            gload16(gp + (size_t)(tid+512)*16,  &lp[(size_t)(tid+512)*8]);
            if (tid < 256) gload16(gp + (size_t)(tid+1024)*16, &lp[(size_t)(tid+1024)*8]);
        }
        const _Float16* tb = SBl[cur];
        if (t != qtile) {
            #pragma unroll
            for (int c3=0;c3<4;++c3){
                const int cl_ = (qt*4+c3)*16 + col;
                half8 b = *(const half8*)&tb[cl_*40 + kg*8];
                f32x4 acc = {0.f,0.f,0.f,0.f};
                acc = __builtin_amdgcn_mfma_f32_16x16x32_f16(afrag, b, acc, 0, 0, 0);
                const unsigned ib = (unsigned)((t<<8)|cl_);
                #pragma unroll
                for (int r=0;r<4;++r){
                    float d2 = fmaxf(acc[r], 0.f);
                    unsigned key = (__float_as_uint(d2) & 0xFFFFC000u) | ib;
                    unsigned lo = s0[r] < key ? s0[r] : key;
                    s1[r] = med3_u32(s0[r], s1[r], key);
                    s0[r] = lo;
                }
            }
        } else {
            #pragma unroll
            for (int c3=0;c3<4;++c3){
                const int cl_ = (qt*4+c3)*16 + col;
                half8 b = *(const half8*)&tb[cl_*40 + kg*8];
                f32x4 acc = {0.f,0.f,0.f,0.f};
                acc = __builtin_amdgcn_mfma_f32_16x16x32_f16(afrag, b, acc, 0, 0, 0);
                const unsigned ib = (unsigned)((t<<8)|cl_);
                #pragma unroll
                for (int r=0;r<4;++r){
                    float d2 = fmaxf(acc[r], 0.f);
                    unsigned key = (__float_as_uint(d2) & 0xFFFFC000u) | ib;
                    if (cl_ == rhs0 + r) key = 0xFFFFFFFFu;
                    unsigned lo = s0[r] < key ? s0[r] : key;
                    s1[r] = med3_u32(s0[r], s1[r], key);
                    s0[r] = lo;
                }
            }
        }
        __syncthreads();
    }

    #pragma unroll
    for (int r=0;r<4;++r){
        const long q = (long)qg*32 + g*16 + kg*4 + r;
        unsigned* pp = &part[((size_t)q*2 + half)*128 + qt*32 + col*2];
        pp[0] = s0[r]; pp[1] = s1[r];
    }
}

// ---------------- kNN merge + passthrough copyout ----------------
__global__ __launch_bounds__(512)
void knn_merge(const unsigned* __restrict__ part,
               int* __restrict__ idx_out, float* __restrict__ w_out,
               const int* __restrict__ gid, const float* __restrict__ gy,
               const int* __restrict__ cid, const float* __restrict__ cy,
               float* __restrict__ out, int N)
{
    const int lane = threadIdx.x & 63, w = threadIdx.x >> 6;
    const long q = (long)blockIdx.x*8 + w;
    const uint4 kk = *reinterpret_cast<const uint4*>(&part[(size_t)q*256 + lane*4]);
    unsigned k0=kk.x, k1=kk.y, k2=kk.z, k3=kk.w;
    unsigned saved = 0;
    #pragma unroll 1
    for (int p=0;p<KNN;++p){
        unsigned a = k0 < k1 ? k0 : k1;
        unsigned b = k2 < k3 ? k2 : k3;
        unsigned lmin = a < b ? a : b;
        unsigned red = wave_umin64(lmin);
        unsigned gm = (unsigned)__builtin_amdgcn_readlane((int)red, 63);
        unsigned long long bal = __ballot(lmin == gm);
        int owner = __ffsll((long long)bal) - 1;
        if (lane == owner){
            if      (k0 == gm) k0 = 0xFFFFFFFFu;
            else if (k1 == gm) k1 = 0xFFFFFFFFu;
            else if (k2 == gm) k2 = 0xFFFFFFFFu;
            else               k3 = 0xFFFFFFFFu;
        }
        if (lane == p) saved = gm;
    }
    if (lane < KNN){
        idx_out[q*KNN + lane] = (int)(saved & 16383u);
        const float d2 = __uint_as_float(saved & 0xFFFFC000u);
        w_out[q*KNN + lane] = expf(-10.f*d2);
    }
    // ---- passthrough outputs (grid-stride over 14N elements) ----
    long i = (long)blockIdx.x*blockDim.x + threadIdx.x;
    long n = N;
    if (i < n)            out[12*n + i]         = (float)gid[i];
    else if (i < 7*n)     out[13*n + (i - n)]   = gy[i - n];
    else if (i < 8*n)     out[19*n + (i - 7*n)] = (float)cid[i - 7*n];
    else if (i < 14*n)    out[20*n + (i - 8*n)] = cy[i - 8*n];
}

// ---------------- F2: GravNet aggregate + lin 56->64 (512 thr) ----------------
__global__ __launch_bounds__(512)
void f2_agg(const float* __restrict__ hg /*pitch 32*/, const int* __restrict__ idx,
            const float* __restrict__ wgt, const float* __restrict__ x12g,
            const float* gWo, const float* gbo, float* __restrict__ xg)
{
    __shared__ int   IDs[64*40];
    __shared__ float Wt[64*40];
    __shared__ float AGG[64*57];
    const int tid = threadIdx.x;
    const long row0 = (long)blockIdx.x*64;
    for (int i=tid;i<64*40;i+=512){ int r=i/40,k=i-r*40;
        IDs[i]=idx[(row0+r)*40+k]; Wt[i]=wgt[(row0+r)*40+k]; }
    for (int i=tid;i<64*12;i+=512){ int r=i/12,c=i-r*12; AGG[r*57+44+c]=x12g[(row0+r)*12+c]; }
    __syncthreads();
    {
        const int r = tid & 63, g = tid >> 6;
        const int f0 = g*4;
        const int nf = (f0 < 22) ? ((22-f0) < 4 ? (22-f0) : 4) : 0;
        float sm[4], mx[4];
        #pragma unroll
        for (int u=0;u<4;++u){ sm[u]=0.f; mx[u]=-INFINITY; }
        if (nf > 0) {
            #pragma unroll 1
            for (int k=0;k<40;++k){
                int j = IDs[r*40+k]; float wv = Wt[r*40+k];
                float4 h0 = *reinterpret_cast<const float4*>(&hg[(long)j*32 + f0]);
                float hv[4] = {h0.x,h0.y,h0.z,h0.w};
                #pragma unroll
                for (int u=0;u<4;++u){ float m = hv[u]*wv; sm[u]+=m; mx[u]=fmaxf(mx[u],m); }
            }
            #pragma unroll
            for (int u=0;u<4;++u) if (u<nf){ AGG[r*57+f0+u]=sm[u]*(1.f/40.f); AGG[r*57+22+f0+u]=mx[u]; }
        }
    }
    __syncthreads();
    lin8<56,64,64,false,512>(AGG,57, gWo, gbo, xg+row0*64,64, tid);
}

// ---------------- F345: GraphConv + nn2 + nn3 fused (64 rows, 1024 thr) ----------------
template<int KP>
__device__ __forceinline__
void mfma_layer(const _Float16* __restrict__ Xl, const _Float16* __restrict__ WTg,
                _Float16* __restrict__ Wl,
                const float* __restrict__ Bv, _Float16* __restrict__ Yl, int tid)
{
    {
        const half8* src = reinterpret_cast<const half8*>(WTg);
        half8* dst = reinterpret_cast<half8*>(Wl);
        constexpr int CHUNKS = 128*KP/8;
        #pragma unroll
        for (int i = tid; i < CHUNKS; i += 1024) dst[i] = src[i];
    }
    __syncthreads();
    const int lane = tid & 63;
    const int wid  = __builtin_amdgcn_readfirstlane(tid >> 6);
    const int m   = wid & 3;
    const int nb  = wid >> 2;
    const int c15 = lane & 15;
    const int kg  = lane >> 4;
    f32x4 acc0 = {0.f,0.f,0.f,0.f};
    f32x4 acc1 = {0.f,0.f,0.f,0.f};
    const _Float16* xb = &Xl[(m*16 + c15)*136];
    const _Float16* w0 = &Wl[(nb*16 + c15)*KP];
    const _Float16* w1 = &Wl[((nb+4)*16 + c15)*KP];
    #pragma unroll
    for (int ks = 0; ks < KP/32; ++ks) {
        const int kb = kg*8 + ks*32;
        half8 a  = *reinterpret_cast<const half8*>(&xb[kb]);
        half8 b0 = *reinterpret_cast<const half8*>(&w0[kb]);
        half8 b1 = *reinterpret_cast<const half8*>(&w1[kb]);
        acc0 = __builtin_amdgcn_mfma_f32_16x16x32_f16(a, b0, acc0, 0, 0, 0);
        acc1 = __builtin_amdgcn_mfma_f32_16x16x32_f16(a, b1, acc1, 0, 0, 0);
    }
    const int drow = m*16 + kg*4;
    const int c0 = nb*16 + c15;
    const int c1 = (nb+4)*16 + c15;
    #pragma unroll
    for (int r = 0; r < 4; ++r) {
        float v0 = (c0 < 126) ? lrelu_f(acc0[r] + Bv[c0]) : 0.f;
        float v1 = (c1 < 126) ? lrelu_f(acc1[r] + Bv[c1]) : 0.f;
        Yl[(drow+r)*136 + c0] = (_Float16)v0;
        Yl[(drow+r)*136 + c1] = (_Float16)v1;
    }
    __syncthreads();
}

__device__ __forceinline__
void lin_out6h(const _Float16* __restrict__ Xs, const float* __restrict__ Wp,
               float* __restrict__ Wl6, const float* __restrict__ Bv,
               float* __restrict__ Y, int ypitch, int tid)
{
    for (int i = tid; i < 126*8; i += 1024) {
        int k = i >> 3, c = i & 7;
        Wl6[i] = Wp[k*16 + c];
    }
    __syncthreads();
    if (tid < 64*6) {
        const int r = tid / 6, c = tid - r*6;
        float acc = Bv[c];
        const _Float16* xrow = &Xs[r*136];
        #pragma unroll 4
        for (int k=0;k<126;++k) acc = fmaf((float)xrow[k], Wl6[k*8+c], acc);
        Y[(long)r*ypitch + c] = lrelu_f(acc);
    }
    __syncthreads();
}

__global__ __launch_bounds__(1024)
void f345(const float* __restrict__ xgin, const int* __restrict__ idx,
          const float* __restrict__ wgt,
          const float* c2Wrel, const float* c2brel, const float* c2Wroot,
          const float* __restrict__ x0,
          const float* __restrict__ wp, const _Float16* __restrict__ wt,
          const float* A_b0,const float* A_b1,const float* A_b2,const float* A_b3,
          const float* B_b0,const float* B_b1,const float* B_b2,const float* B_b3,
          float* __restrict__ outIds, float* __restrict__ outP4)
{
    __shared__ float XCs[64*65];                      // persistent xc (fp32)
    __shared__ __align__(16) char uni[69120];         // phase-union scratch
    // f3 view
    int*   IDs = (int*)uni;                           // 10240 B
    float* Wt  = (float*)(uni+10240);                 // 10240 B
    float* NB  = (float*)(uni+20480);                 // 16640 B
    float* XGs = (float*)(uni+37120);                 // 16640 B
    // f45 view
    _Float16* bufA = (_Float16*)uni;                  // 17408 B
    _Float16* bufB = (_Float16*)(uni+17408);          // 17408 B
    _Float16* Wl   = (_Float16*)(uni+34816);          // 32768 B
    float*    IDS6 = (float*)(uni+67584);             // 1536 B

    const int tid = threadIdx.x;
    const long row0 = (long)blockIdx.x*64;
    // ---- f3: gather + dual linear -> XCs ----
    for (int i=tid;i<64*40;i+=1024){ int r=i/40,k=i-r*40;
        IDs[i]=idx[(row0+r)*40+k]; Wt[i]=wgt[(row0+r)*40+k]; }
    for (int i=tid;i<64*64;i+=1024){ int r=i>>6,c=i&63; XGs[r*65+c]=xgin[(row0+r)*64+c]; }
    __syncthreads();
    {
        const int r = tid & 63, g = tid >> 6;   // g in 0..15, cols [4g,4g+4)
        float acc[4] = {0.f,0.f,0.f,0.f};
        #pragma unroll 1
        for (int k=0;k<40;++k){
            int j = IDs[r*40+k]; float wv = Wt[r*40+k];
            float4 v = *reinterpret_cast<const float4*>(&xgin[(long)j*64 + g*4]);
            acc[0]=fmaf(v.x,wv,acc[0]); acc[1]=fmaf(v.y,wv,acc[1]);
            acc[2]=fmaf(v.z,wv,acc[2]); acc[3]=fmaf(v.w,wv,acc[3]);
        }
        __syncthreads();
        #pragma unroll
        for (int j=0;j<4;++j) NB[r*65 + g*4 + j] = acc[j];
    }
    __syncthreads();
    lin8_dual<64,64,64,1024>(NB,65, XGs,65, c2Wrel,c2brel,c2Wroot, XCs,65, tid);
    // ---- f45: nn2 ----
    for (int i=tid;i<64*64;i+=1024){ int r=i>>6,c=i&63;
        bufA[r*136+c] = (_Float16)XCs[r*65+c]; }
    __syncthreads();
    mfma_layer<64>(bufA, wt+T_N2W0, Wl, A_b0, bufB, tid);
    mfma_layer<128>(bufB, wt+T_N2W1, Wl, A_b1, bufA, tid);
    mfma_layer<128>(bufA, wt+T_N2W2, Wl, A_b2, bufB, tid);
    lin_out6h(bufB, wp+PAD_OFF_N2W3, (float*)Wl, A_b3, IDS6, 6, tid);
    for (int i=tid;i<64*6;i+=1024){ int r=i/6,c=i-r*6; outIds[(row0+r)*6+c]=IDS6[i]; }
    // ---- concat [xc, ids, x0] -> bufA (96 cols) ----
    for (int i=tid;i<64*96;i+=1024){
        int r=i/96, c=i-r*96;
        float v;
        if (c < 64)      v = XCs[r*65 + c];
        else if (c < 70) v = IDS6[r*6 + (c-64)];
        else if (c < 82) v = x0[(row0+r)*12 + (c-70)];
        else             v = 0.f;
        bufA[r*136+c] = (_Float16)v;
    }
    __syncthreads();
    // ---- nn3 ----
    mfma_layer<96>(bufA, wt+T_N3W0, Wl, B_b0, bufB, tid);
    mfma_layer<128>(bufB, wt+T_N3W1, Wl, B_b1, bufA, tid);
    mfma_layer<128>(bufA, wt+T_N3W2, Wl, B_b2, bufB, tid);
    lin_out6h(bufB, wp+PAD_OFF_N3W3, (float*)Wl, B_b3, outP4+row0*6, 6, tid);
}

extern "C" void kernel_launch(void* const* d_in, const int* in_sizes, int n_in,
                              void* d_out, int out_size, void* d_ws, size_t ws_size,
                              hipStream_t stream)
{
    const float* x0     = (const float*)d_in[0];
    const float* ygen   = (const float*)d_in[1];
    const float* ycand  = (const float*)d_in[2];
    const int*   ygenid = (const int*)d_in[3];
    const int*   ycandid= (const int*)d_in[4];
    const float* n1W0=(const float*)d_in[5],  *n1b0=(const float*)d_in[6];
    const float* n1W1=(const float*)d_in[7],  *n1b1=(const float*)d_in[8];
    const float* n1W2=(const float*)d_in[9],  *n1b2=(const float*)d_in[10];
    const float* gWs =(const float*)d_in[11], *gbs =(const float*)d_in[12];
    const float* gWh =(const float*)d_in[13], *gbh =(const float*)d_in[14];
    const float* gWo =(const float*)d_in[15], *gbo =(const float*)d_in[16];
    const float* c2Wrel=(const float*)d_in[17], *c2brel=(const float*)d_in[18];
    const float* c2Wroot=(const float*)d_in[19];
    const float* n2W0=(const float*)d_in[20], *n2b0=(const float*)d_in[21];
    const float* n2W1=(const float*)d_in[22], *n2b1=(const float*)d_in[23];
    const float* n2W2=(const float*)d_in[24], *n2b2=(const float*)d_in[25];
    const float* n2W3=(const float*)d_in[26], *n2b3=(const float*)d_in[27];
    const float* n3W0=(const float*)d_in[28], *n3b0=(const float*)d_in[29];
    const float* n3W1=(const float*)d_in[30], *n3b1=(const float*)d_in[31];
    const float* n3W2=(const float*)d_in[32], *n3b2=(const float*)d_in[33];
    const float* n3W3=(const float*)d_in[34], *n3b3=(const float*)d_in[35];

    const int N = in_sizes[0] / 12;      // 16384
    float* ws = (float*)d_ws;
    size_t off = 0;
    auto alloc = [&](size_t cnt){ float* p = ws + off; off += cnt; return p; };
    float* padw = alloc(PAD_TOTAL);
    _Float16* wt16 = (_Float16*)alloc((T_TOTAL+1)/2 + 8);
    float* x12  = alloc((size_t)N*12);
    _Float16* SA16 = (_Float16*)alloc((size_t)N*16);
    _Float16* SB16 = (_Float16*)alloc((size_t)N*20);
    float* h    = alloc((size_t)N*32);
    unsigned* part = (unsigned*)alloc((size_t)N*256);
    int*   idxb = (int*)alloc((size_t)N*KNN);
    float* wb   = alloc((size_t)N*KNN);
    float* xg   = alloc((size_t)N*64);
    (void)ws_size; (void)n_in; (void)out_size;

    float* outF = (float*)d_out;
    const int GB = N / 64;               // 256 blocks

    pad_all<<<(PAD_TOTAL+T_TOTAL+255)/256,256,0,stream>>>(gWs,gWh,n1W2,n2W3,n3W3,
                                                          n2W0,n2W1,n2W2,n3W0,n3W1,n3W2,
                                                          padw, wt16);
    f1_encoder<<<GB,512,0,stream>>>(x0, padw, n1W0,n1b0, n1W1,n1b1, n1b2,
                                    gbs, gbh, x12, SA16, SB16, h);
    knn_scan<<<(N/32)*2, 512, 0, stream>>>(SA16, SB16, part, N);
    knn_merge<<<N/8, 512, 0, stream>>>(part, idxb, wb,
                                       ygenid, ygen, ycandid, ycand, outF, N);
    f2_agg<<<GB,512,0,stream>>>(h, idxb, wb, x12, gWo, gbo, xg);
    f345<<<GB,1024,0,stream>>>(xg, idxb, wb, c2Wrel, c2brel, c2Wroot, x0, padw, wt16,
                               n2b0,n2b1,n2b2,n2b3, n3b0,n3b1,n3b2,n3b3,
                               outF, outF + (size_t)N*6);
}

// Round 19
// 199.860 us; speedup vs baseline: 1.0506x; 1.0097x over previous
//
#include <hip/hip_runtime.h>
#include <math.h>

static constexpr int KNN = 40;

__device__ __forceinline__ float lrelu_f(float v){ return v >= 0.f ? v : 0.5f*v; }

typedef _Float16 half8 __attribute__((ext_vector_type(8)));
typedef float    f32x4 __attribute__((ext_vector_type(4)));

__device__ __forceinline__ void gload16(const void* g, void* l){
    __builtin_amdgcn_global_load_lds((const __attribute__((address_space(1))) void*)g,
                                     (__attribute__((address_space(3))) void*)l, 16, 0, 0);
}

// ---- fp32 padded-weight offsets (floats) ----
#define PAD_OFF_GWS   0
#define PAD_OFF_GWH   192
#define PAD_OFF_N1W2  576
#define PAD_OFF_N2W3  1600
#define PAD_OFF_N3W3  3616
#define PAD_TOTAL     5632

// ---- fp16 transposed weight offsets (halves): WT[n][k], n padded to 128 ----
#define T_N2W0  0
#define T_N2W1  8192
#define T_N2W2  24576
#define T_N3W0  40960
#define T_N3W1  53248
#define T_N3W2  69632
#define T_TOTAL 86016

__global__ void pad_all(const float* gWs,const float* gWh,const float* n1W2,
                        const float* n2W3,const float* n3W3,
                        const float* n2W0,const float* n2W1,const float* n2W2,
                        const float* n3W0,const float* n3W1,const float* n3W2,
                        float* __restrict__ wp, _Float16* __restrict__ wt)
{
    int i = blockIdx.x*blockDim.x + threadIdx.x;
    if (i < PAD_TOTAL) {
        const float* src; int cols, sh, off;
        if      (i < PAD_OFF_GWH)  { src=gWs;  cols=8;  sh=4; off=PAD_OFF_GWS;  }
        else if (i < PAD_OFF_N1W2) { src=gWh;  cols=22; sh=5; off=PAD_OFF_GWH;  }
        else if (i < PAD_OFF_N2W3) { src=n1W2; cols=12; sh=4; off=PAD_OFF_N1W2; }
        else if (i < PAD_OFF_N3W3) { src=n2W3; cols=6;  sh=4; off=PAD_OFF_N2W3; }
        else                       { src=n3W3; cols=6;  sh=4; off=PAD_OFF_N3W3; }
        int li = i - off;
        int r = li >> sh, c = li & ((1<<sh)-1);
        wp[i] = (c < cols) ? src[r*cols + c] : 0.f;
        return;
    }
    int j = i - PAD_TOTAL;
    if (j >= T_TOTAL) return;
    const float* src; int KP, K, off;
    if      (j < T_N2W1) { src=n2W0; KP=64;  K=64;  off=T_N2W0; }
    else if (j < T_N2W2) { src=n2W1; KP=128; K=126; off=T_N2W1; }
    else if (j < T_N3W0) { src=n2W2; KP=128; K=126; off=T_N2W2; }
    else if (j < T_N3W1) { src=n3W0; KP=96;  K=82;  off=T_N3W0; }
    else if (j < T_N3W2) { src=n3W1; KP=128; K=126; off=T_N3W1; }
    else                 { src=n3W2; KP=128; K=126; off=T_N3W2; }
    int li = j - off;
    int n = li / KP, k = li - n*KP;
    float v = (n < 126 && k < K) ? src[k*126 + n] : 0.f;
    wt[j] = (_Float16)v;
}

// ---- lin8: wave owns 8 output cols -> wave-uniform W addresses (64 rows) ----
template<int K, int NOUT, int WPITCH, bool RELU, int NTH>
__device__ __forceinline__
void lin8(const float* __restrict__ Xs, int xpitch,
          const float* __restrict__ W, const float* __restrict__ Bv,
          float* __restrict__ Y, int ypitch, int tid)
{
    constexpr int NP  = ((NOUT+7)/8)*8;
    constexpr int NCG = NP/8;
    constexpr int NW  = NTH/64;
    const int lane = tid & 63;
    for (int g0 = tid >> 6; g0 < NCG; g0 += NW) {
        const int cg = __builtin_amdgcn_readfirstlane(g0);
        float acc[8];
        #pragma unroll
        for (int j=0;j<8;++j){ int c=cg*8+j; acc[j] = (c < NOUT) ? Bv[c] : 0.f; }
        const float* xrow = &Xs[(long)lane*xpitch];
        const float* wp = &W[cg*8];
        #pragma unroll 4
        for (int k=0;k<K;++k){
            const float xv = xrow[k];
            const float4* w4 = reinterpret_cast<const float4*>(wp + (long)k*WPITCH);
            float4 a = w4[0], b = w4[1];
            acc[0]=fmaf(xv,a.x,acc[0]); acc[1]=fmaf(xv,a.y,acc[1]);
            acc[2]=fmaf(xv,a.z,acc[2]); acc[3]=fmaf(xv,a.w,acc[3]);
            acc[4]=fmaf(xv,b.x,acc[4]); acc[5]=fmaf(xv,b.y,acc[5]);
            acc[6]=fmaf(xv,b.z,acc[6]); acc[7]=fmaf(xv,b.w,acc[7]);
        }
        #pragma unroll
        for (int j=0;j<8;++j){
            int c = cg*8 + j;
            if (c < NOUT){ float v = acc[j]; if (RELU) v = lrelu_f(v); Y[(long)lane*ypitch + c] = v; }
        }
    }
    __syncthreads();
}

template<int K, int NOUT, int WPITCH, int NTH>
__device__ __forceinline__
void lin8_dual(const float* __restrict__ Xs, int xp, const float* __restrict__ X2s, int xp2,
               const float* __restrict__ W, const float* __restrict__ Bv, const float* __restrict__ W2,
               float* __restrict__ Y, int ypitch, int tid)
{
    constexpr int NP  = ((NOUT+7)/8)*8;
    constexpr int NCG = NP/8;
    constexpr int NW  = NTH/64;
    const int lane = tid & 63;
    for (int g0 = tid >> 6; g0 < NCG; g0 += NW) {
        const int cg = __builtin_amdgcn_readfirstlane(g0);
        float acc[8];
        #pragma unroll
        for (int j=0;j<8;++j){ int c=cg*8+j; acc[j] = (c < NOUT) ? Bv[c] : 0.f; }
        {
            const float* xrow = &Xs[(long)lane*xp];
            const float* wp = &W[cg*8];
            #pragma unroll 4
            for (int k=0;k<K;++k){
                const float xv = xrow[k];
                const float4* w4 = reinterpret_cast<const float4*>(wp + (long)k*WPITCH);
                float4 a = w4[0], b = w4[1];
                acc[0]=fmaf(xv,a.x,acc[0]); acc[1]=fmaf(xv,a.y,acc[1]);
                acc[2]=fmaf(xv,a.z,acc[2]); acc[3]=fmaf(xv,a.w,acc[3]);
                acc[4]=fmaf(xv,b.x,acc[4]); acc[5]=fmaf(xv,b.y,acc[5]);
                acc[6]=fmaf(xv,b.z,acc[6]); acc[7]=fmaf(xv,b.w,acc[7]);
            }
        }
        {
            const float* xrow = &X2s[(long)lane*xp2];
            const float* wp = &W2[cg*8];
            #pragma unroll 4
            for (int k=0;k<K;++k){
                const float xv = xrow[k];
                const float4* w4 = reinterpret_cast<const float4*>(wp + (long)k*WPITCH);
                float4 a = w4[0], b = w4[1];
                acc[0]=fmaf(xv,a.x,acc[0]); acc[1]=fmaf(xv,a.y,acc[1]);
                acc[2]=fmaf(xv,a.z,acc[2]); acc[3]=fmaf(xv,a.w,acc[3]);
                acc[4]=fmaf(xv,b.x,acc[4]); acc[5]=fmaf(xv,b.y,acc[5]);
                acc[6]=fmaf(xv,b.z,acc[6]); acc[7]=fmaf(xv,b.w,acc[7]);
            }
        }
        #pragma unroll
        for (int j=0;j<8;++j){
            int c = cg*8 + j;
            if (c < NOUT) Y[(long)lane*ypitch + c] = acc[j];
        }
    }
    __syncthreads();
}

// ---------------- F1: nn1 encoder + gWs + gWh + SA/SB build (512 thr) ----------------
__global__ __launch_bounds__(512)
void f1_encoder(const float* __restrict__ x0, const float* __restrict__ wp,
                const float* n1W0,const float* n1b0,const float* n1W1,const float* n1b1,
                const float* n1b2, const float* gbs, const float* gbh,
                float* __restrict__ x12g,
                _Float16* __restrict__ SA16, _Float16* __restrict__ SB16 /*pitch 40*/,
                float* __restrict__ hg /*pitch 32*/)
{
    __shared__ float A1[64*65], A2[64*65], Ss[64*9];
    const int tid = threadIdx.x;
    const long row0 = (long)blockIdx.x*64;
    lin8<12,64,64,true,512>(x0+row0*12,12, n1W0, n1b0, A1,65, tid);
    lin8<64,64,64,true,512>(A1,65, n1W1, n1b1, A2,65, tid);
    lin8<64,12,16,true,512>(A2,65, wp+PAD_OFF_N1W2, n1b2, A1,13, tid);
    for (int i=tid;i<64*12;i+=512){ int r=i/12,c=i-r*12; x12g[(row0+r)*12+c]=A1[r*13+c]; }
    lin8<12,8,16,false,512>(A1,13, wp+PAD_OFF_GWS, gbs, Ss,9, tid);
    lin8<12,22,32,false,512>(A1,13, wp+PAD_OFF_GWH, gbh, hg+row0*32,32, tid);
    if (tid < 64) {
        const long node = row0 + tid;
        float sv[8]; float nq = 0.f;
        #pragma unroll
        for (int k=0;k<8;++k){ float v=Ss[tid*9+k]; sv[k]=v; nq=fmaf(v,v,nq); }
        _Float16 ch[8], clo[8];
        #pragma unroll
        for (int k=0;k<8;++k){ ch[k]=(_Float16)sv[k]; clo[k]=(_Float16)(sv[k]-(float)ch[k]); }
        _Float16 nh = (_Float16)nq, nl = (_Float16)(nq-(float)nh);
        const _Float16 one = (_Float16)1.f, zero = (_Float16)0.f;
        half8 a0,a1,a2,b0,b2;
        #pragma unroll
        for (int k=0;k<8;++k){
            a0[k]=ch[k]; a1[k]=clo[k]; a2[k]=ch[k];
            b0[k]=(_Float16)(-2.f*(float)ch[k]);
            b2[k]=(_Float16)(-2.f*(float)clo[k]);
        }
        half8 a3 = {nh, nl, one, one, zero, zero, zero, zero};
        half8 b3 = {one, one, nh, nl, zero, zero, zero, zero};
        half8* ap = (half8*)&SA16[(size_t)node*32];
        ap[0]=a0; ap[1]=a1; ap[2]=a2; ap[3]=a3;
        half8* bp = (half8*)&SB16[(size_t)node*40];
        bp[0]=b0; bp[1]=b0; bp[2]=b2; bp[3]=b3;
        bp[4]=half8{zero,zero,zero,zero,zero,zero,zero,zero};
    }
}

// ---------------- kNN scan: 64 queries/block, 16 waves ----------------
template<int C>
__device__ __forceinline__ unsigned dpp_umin(unsigned x){
    unsigned y = (unsigned)__builtin_amdgcn_update_dpp((int)x, (int)x, C, 0xf, 0xf, false);
    return x < y ? x : y;
}
__device__ __forceinline__ unsigned wave_umin64(unsigned x){
    x = dpp_umin<0x111>(x);
    x = dpp_umin<0x112>(x);
    x = dpp_umin<0x114>(x);
    x = dpp_umin<0x118>(x);
    x = dpp_umin<0x142>(x);
    x = dpp_umin<0x143>(x);
    return x;
}
__device__ __forceinline__ unsigned med3_u32(unsigned a, unsigned b, unsigned c){
    unsigned d;
    asm("v_med3_u32 %0, %1, %2, %3" : "=v"(d) : "v"(a), "v"(b), "v"(c));
    return d;
}

// grid: (N/64)*2 blocks of 1024. Block b: 64 queries (qg=b>>1), half b&1 (32 tiles).
// wave w: query group g=w>>2 (16 queries), candidate quarter qt=w&3.
__global__ __launch_bounds__(1024)
void knn_scan(const _Float16* __restrict__ SA, const _Float16* __restrict__ SB,
              unsigned* __restrict__ part, int N)
{
    __shared__ __align__(16) _Float16 SBl[2][256*40];
    const int tid  = threadIdx.x;
    const int lane = tid & 63;
    const int w    = tid >> 6;
    const int g    = w >> 2, qt = w & 3;
    const int col  = lane & 15, kg = lane >> 4;
    const int qg   = blockIdx.x >> 1, half = blockIdx.x & 1;
    const int qb   = qg*64 + g*16;
    const int qtile = qb >> 8;
    const int rhs0  = (qb & 255) + kg*4;
    const int T0 = half*32;

    half8 afrag = *(const half8*)&SA[(size_t)(qb + col)*32 + kg*8];
    unsigned s0[4], s1[4];
    #pragma unroll
    for (int r=0;r<4;++r){ s0[r]=0xFFFFFFFFu; s1[r]=0xFFFFFFFFu; }

    {
        const char* gp = (const char*)(SB + (size_t)T0*256*40);
        gload16(gp + (size_t)tid*16, &SBl[0][(size_t)tid*8]);
        if (tid < 256) gload16(gp + (size_t)(tid+1024)*16, &SBl[0][(size_t)(tid+1024)*8]);
    }
    __syncthreads();
    #pragma unroll 1
    for (int t = T0; t < T0+32; ++t) {
        const int cur = t & 1;
        if (t+1 < T0+32) {
            const char* gp = (const char*)(SB + (size_t)(t+1)*256*40);
            _Float16* lp = SBl[cur^1];
            gload16(gp + (size_t)tid*16, &lp[(size_t)tid*8]);
            if (tid < 256) gload16(gp + (size_t)(tid+1024)*16, &lp[(size_t)(tid+1024)*8]);
        }
        const _Float16* tb = SBl[cur];
        if (t != qtile) {
            #pragma unroll
            for (int c3=0;c3<4;++c3){
                const int cl_ = (qt*4+c3)*16 + col;
                half8 b = *(const half8*)&tb[cl_*40 + kg*8];
                f32x4 acc = {0.f,0.f,0.f,0.f};
                acc = __builtin_amdgcn_mfma_f32_16x16x32_f16(afrag, b, acc, 0, 0, 0);
                const unsigned ib = (unsigned)((t<<8)|cl_);
                #pragma unroll
                for (int r=0;r<4;++r){
                    float d2 = fmaxf(acc[r], 0.f);
                    unsigned key = (__float_as_uint(d2) & 0xFFFFC000u) | ib;
                    unsigned lo = s0[r] < key ? s0[r] : key;
                    s1[r] = med3_u32(s0[r], s1[r], key);
                    s0[r] = lo;
                }
            }
        } else {
            #pragma unroll
            for (int c3=0;c3<4;++c3){
                const int cl_ = (qt*4+c3)*16 + col;
                half8 b = *(const half8*)&tb[cl_*40 + kg*8];
                f32x4 acc = {0.f,0.f,0.f,0.f};
                acc = __builtin_amdgcn_mfma_f32_16x16x32_f16(afrag, b, acc, 0, 0, 0);
                const unsigned ib = (unsigned)((t<<8)|cl_);
                #pragma unroll
                for (int r=0;r<4;++r){
                    float d2 = fmaxf(acc[r], 0.f);
                    unsigned key = (__float_as_uint(d2) & 0xFFFFC000u) | ib;
                    if (cl_ == rhs0 + r) key = 0xFFFFFFFFu;
                    unsigned lo = s0[r] < key ? s0[r] : key;
                    s1[r] = med3_u32(s0[r], s1[r], key);
                    s0[r] = lo;
                }
            }
        }
        __syncthreads();
    }

    #pragma unroll
    for (int r=0;r<4;++r){
        const long q = (long)qg*64 + g*16 + kg*4 + r;
        unsigned* pp = &part[((size_t)q*2 + half)*128 + qt*32 + col*2];
        pp[0] = s0[r]; pp[1] = s1[r];
    }
}

// ---------------- kNN merge + passthrough copyout ----------------
__global__ __launch_bounds__(512)
void knn_merge(const unsigned* __restrict__ part,
               int* __restrict__ idx_out, float* __restrict__ w_out,
               const int* __restrict__ gid, const float* __restrict__ gy,
               const int* __restrict__ cid, const float* __restrict__ cy,
               float* __restrict__ out, int N)
{
    const int lane = threadIdx.x & 63, w = threadIdx.x >> 6;
    const long q = (long)blockIdx.x*8 + w;
    const uint4 kk = *reinterpret_cast<const uint4*>(&part[(size_t)q*256 + lane*4]);
    unsigned k0=kk.x, k1=kk.y, k2=kk.z, k3=kk.w;
    unsigned saved = 0;
    #pragma unroll 1
    for (int p=0;p<KNN;++p){
        unsigned a = k0 < k1 ? k0 : k1;
        unsigned b = k2 < k3 ? k2 : k3;
        unsigned lmin = a < b ? a : b;
        unsigned red = wave_umin64(lmin);
        unsigned gm = (unsigned)__builtin_amdgcn_readlane((int)red, 63);
        unsigned long long bal = __ballot(lmin == gm);
        int owner = __ffsll((long long)bal) - 1;
        if (lane == owner){
            if      (k0 == gm) k0 = 0xFFFFFFFFu;
            else if (k1 == gm) k1 = 0xFFFFFFFFu;
            else if (k2 == gm) k2 = 0xFFFFFFFFu;
            else               k3 = 0xFFFFFFFFu;
        }
        if (lane == p) saved = gm;
    }
    if (lane < KNN){
        idx_out[q*KNN + lane] = (int)(saved & 16383u);
        const float d2 = __uint_as_float(saved & 0xFFFFC000u);
        w_out[q*KNN + lane] = expf(-10.f*d2);
    }
    // ---- passthrough outputs ----
    long i = (long)blockIdx.x*blockDim.x + threadIdx.x;
    long n = N;
    if (i < n)            out[12*n + i]         = (float)gid[i];
    else if (i < 7*n)     out[13*n + (i - n)]   = gy[i - n];
    else if (i < 8*n)     out[19*n + (i - 7*n)] = (float)cid[i - 7*n];
    else if (i < 14*n)    out[20*n + (i - 8*n)] = cy[i - 8*n];
}

// ---------------- F2: GravNet aggregate + lin 56->64 (512 thr) ----------------
__global__ __launch_bounds__(512)
void f2_agg(const float* __restrict__ hg /*pitch 32*/, const int* __restrict__ idx,
            const float* __restrict__ wgt, const float* __restrict__ x12g,
            const float* gWo, const float* gbo, float* __restrict__ xg)
{
    __shared__ int   IDs[64*40];
    __shared__ float Wt[64*40];
    __shared__ float AGG[64*57];
    const int tid = threadIdx.x;
    const long row0 = (long)blockIdx.x*64;
    for (int i=tid;i<64*40;i+=512){ int r=i/40,k=i-r*40;
        IDs[i]=idx[(row0+r)*40+k]; Wt[i]=wgt[(row0+r)*40+k]; }
    for (int i=tid;i<64*12;i+=512){ int r=i/12,c=i-r*12; AGG[r*57+44+c]=x12g[(row0+r)*12+c]; }
    __syncthreads();
    {
        const int r = tid & 63, g = tid >> 6;
        const int f0 = g*4;
        const int nf = (f0 < 22) ? ((22-f0) < 4 ? (22-f0) : 4) : 0;
        float sm[4], mx[4];
        #pragma unroll
        for (int u=0;u<4;++u){ sm[u]=0.f; mx[u]=-INFINITY; }
        if (nf > 0) {
            #pragma unroll 1
            for (int k=0;k<40;++k){
                int j = IDs[r*40+k]; float wv = Wt[r*40+k];
                float4 h0 = *reinterpret_cast<const float4*>(&hg[(long)j*32 + f0]);
                float hv[4] = {h0.x,h0.y,h0.z,h0.w};
                #pragma unroll
                for (int u=0;u<4;++u){ float m = hv[u]*wv; sm[u]+=m; mx[u]=fmaxf(mx[u],m); }
            }
            #pragma unroll
            for (int u=0;u<4;++u) if (u<nf){ AGG[r*57+f0+u]=sm[u]*(1.f/40.f); AGG[r*57+22+f0+u]=mx[u]; }
        }
    }
    __syncthreads();
    lin8<56,64,64,false,512>(AGG,57, gWo, gbo, xg+row0*64,64, tid);
}

// ---------------- F345: GraphConv + nn2 + nn3 fused (64 rows, 1024 thr) ----------------
template<int KP>
__device__ __forceinline__
void mfma_layer(const _Float16* __restrict__ Xl, const _Float16* __restrict__ WTg,
                _Float16* __restrict__ Wl,
                const float* __restrict__ Bv, _Float16* __restrict__ Yl, int tid)
{
    {
        const half8* src = reinterpret_cast<const half8*>(WTg);
        half8* dst = reinterpret_cast<half8*>(Wl);
        constexpr int CHUNKS = 128*KP/8;
        #pragma unroll
        for (int i = tid; i < CHUNKS; i += 1024) dst[i] = src[i];
    }
    __syncthreads();
    const int lane = tid & 63;
    const int wid  = __builtin_amdgcn_readfirstlane(tid >> 6);
    const int m   = wid & 3;
    const int nb  = wid >> 2;
    const int c15 = lane & 15;
    const int kg  = lane >> 4;
    f32x4 acc0 = {0.f,0.f,0.f,0.f};
    f32x4 acc1 = {0.f,0.f,0.f,0.f};
    const _Float16* xb = &Xl[(m*16 + c15)*136];
    const _Float16* w0 = &Wl[(nb*16 + c15)*KP];
    const _Float16* w1 = &Wl[((nb+4)*16 + c15)*KP];
    #pragma unroll
    for (int ks = 0; ks < KP/32; ++ks) {
        const int kb = kg*8 + ks*32;
        half8 a  = *reinterpret_cast<const half8*>(&xb[kb]);
        half8 b0 = *reinterpret_cast<const half8*>(&w0[kb]);
        half8 b1 = *reinterpret_cast<const half8*>(&w1[kb]);
        acc0 = __builtin_amdgcn_mfma_f32_16x16x32_f16(a, b0, acc0, 0, 0, 0);
        acc1 = __builtin_amdgcn_mfma_f32_16x16x32_f16(a, b1, acc1, 0, 0, 0);
    }
    const int drow = m*16 + kg*4;
    const int c0 = nb*16 + c15;
    const int c1 = (nb+4)*16 + c15;
    #pragma unroll
    for (int r = 0; r < 4; ++r) {
        float v0 = (c0 < 126) ? lrelu_f(acc0[r] + Bv[c0]) : 0.f;
        float v1 = (c1 < 126) ? lrelu_f(acc1[r] + Bv[c1]) : 0.f;
        Yl[(drow+r)*136 + c0] = (_Float16)v0;
        Yl[(drow+r)*136 + c1] = (_Float16)v1;
    }
    __syncthreads();
}

__device__ __forceinline__
void lin_out6h(const _Float16* __restrict__ Xs, const float* __restrict__ Wp,
               float* __restrict__ Wl6, const float* __restrict__ Bv,
               float* __restrict__ Y, int ypitch, int tid)
{
    for (int i = tid; i < 126*8; i += 1024) {
        int k = i >> 3, c = i & 7;
        Wl6[i] = Wp[k*16 + c];
    }
    __syncthreads();
    if (tid < 64*6) {
        const int r = tid / 6, c = tid - r*6;
        float acc = Bv[c];
        const _Float16* xrow = &Xs[r*136];
        #pragma unroll 4
        for (int k=0;k<126;++k) acc = fmaf((float)xrow[k], Wl6[k*8+c], acc);
        Y[(long)r*ypitch + c] = lrelu_f(acc);
    }
    __syncthreads();
}

__global__ __launch_bounds__(1024)
void f345(const float* __restrict__ xgin, const int* __restrict__ idx,
          const float* __restrict__ wgt,
          const float* c2Wrel, const float* c2brel, const float* c2Wroot,
          const float* __restrict__ x0,
          const float* __restrict__ wp, const _Float16* __restrict__ wt,
          const float* A_b0,const float* A_b1,const float* A_b2,const float* A_b3,
          const float* B_b0,const float* B_b1,const float* B_b2,const float* B_b3,
          float* __restrict__ outIds, float* __restrict__ outP4)
{
    __shared__ float XCs[64*65];
    __shared__ __align__(16) char uni[69120];
    int*   IDs = (int*)uni;
    float* Wt  = (float*)(uni+10240);
    float* NB  = (float*)(uni+20480);
    float* XGs = (float*)(uni+37120);
    _Float16* bufA = (_Float16*)uni;
    _Float16* bufB = (_Float16*)(uni+17408);
    _Float16* Wl   = (_Float16*)(uni+34816);
    float*    IDS6 = (float*)(uni+67584);

    const int tid = threadIdx.x;
    const long row0 = (long)blockIdx.x*64;
    for (int i=tid;i<64*40;i+=1024){ int r=i/40,k=i-r*40;
        IDs[i]=idx[(row0+r)*40+k]; Wt[i]=wgt[(row0+r)*40+k]; }
    for (int i=tid;i<64*64;i+=1024){ int r=i>>6,c=i&63; XGs[r*65+c]=xgin[(row0+r)*64+c]; }
    __syncthreads();
    {
        const int r = tid & 63, g = tid >> 6;
        float acc[4] = {0.f,0.f,0.f,0.f};
        #pragma unroll 1
        for (int k=0;k<40;++k){
            int j = IDs[r*40+k]; float wv = Wt[r*40+k];
            float4 v = *reinterpret_cast<const float4*>(&xgin[(long)j*64 + g*4]);
            acc[0]=fmaf(v.x,wv,acc[0]); acc[1]=fmaf(v.y,wv,acc[1]);
            acc[2]=fmaf(v.z,wv,acc[2]); acc[3]=fmaf(v.w,wv,acc[3]);
        }
        __syncthreads();
        #pragma unroll
        for (int j=0;j<4;++j) NB[r*65 + g*4 + j] = acc[j];
    }
    __syncthreads();
    lin8_dual<64,64,64,1024>(NB,65, XGs,65, c2Wrel,c2brel,c2Wroot, XCs,65, tid);
    for (int i=tid;i<64*64;i+=1024){ int r=i>>6,c=i&63;
        bufA[r*136+c] = (_Float16)XCs[r*65+c]; }
    __syncthreads();
    mfma_layer<64>(bufA, wt+T_N2W0, Wl, A_b0, bufB, tid);
    mfma_layer<128>(bufB, wt+T_N2W1, Wl, A_b1, bufA, tid);
    mfma_layer<128>(bufA, wt+T_N2W2, Wl, A_b2, bufB, tid);
    lin_out6h(bufB, wp+PAD_OFF_N2W3, (float*)Wl, A_b3, IDS6, 6, tid);
    for (int i=tid;i<64*6;i+=1024){ int r=i/6,c=i-r*6; outIds[(row0+r)*6+c]=IDS6[i]; }
    for (int i=tid;i<64*96;i+=1024){
        int r=i/96, c=i-r*96;
        float v;
        if (c < 64)      v = XCs[r*65 + c];
        else if (c < 70) v = IDS6[r*6 + (c-64)];
        else if (c < 82) v = x0[(row0+r)*12 + (c-70)];
        else             v = 0.f;
        bufA[r*136+c] = (_Float16)v;
    }
    __syncthreads();
    mfma_layer<96>(bufA, wt+T_N3W0, Wl, B_b0, bufB, tid);
    mfma_layer<128>(bufB, wt+T_N3W1, Wl, B_b1, bufA, tid);
    mfma_layer<128>(bufA, wt+T_N3W2, Wl, B_b2, bufB, tid);
    lin_out6h(bufB, wp+PAD_OFF_N3W3, (float*)Wl, B_b3, outP4+row0*6, 6, tid);
}

extern "C" void kernel_launch(void* const* d_in, const int* in_sizes, int n_in,
                              void* d_out, int out_size, void* d_ws, size_t ws_size,
                              hipStream_t stream)
{
    const float* x0     = (const float*)d_in[0];
    const float* ygen   = (const float*)d_in[1];
    const float* ycand  = (const float*)d_in[2];
    const int*   ygenid = (const int*)d_in[3];
    const int*   ycandid= (const int*)d_in[4];
    const float* n1W0=(const float*)d_in[5],  *n1b0=(const float*)d_in[6];
    const float* n1W1=(const float*)d_in[7],  *n1b1=(const float*)d_in[8];
    const float* n1W2=(const float*)d_in[9],  *n1b2=(const float*)d_in[10];
    const float* gWs =(const float*)d_in[11], *gbs =(const float*)d_in[12];
    const float* gWh =(const float*)d_in[13], *gbh =(const float*)d_in[14];
    const float* gWo =(const float*)d_in[15], *gbo =(const float*)d_in[16];
    const float* c2Wrel=(const float*)d_in[17], *c2brel=(const float*)d_in[18];
    const float* c2Wroot=(const float*)d_in[19];
    const float* n2W0=(const float*)d_in[20], *n2b0=(const float*)d_in[21];
    const float* n2W1=(const float*)d_in[22], *n2b1=(const float*)d_in[23];
    const float* n2W2=(const float*)d_in[24], *n2b2=(const float*)d_in[25];
    const float* n2W3=(const float*)d_in[26], *n2b3=(const float*)d_in[27];
    const float* n3W0=(const float*)d_in[28], *n3b0=(const float*)d_in[29];
    const float* n3W1=(const float*)d_in[30], *n3b1=(const float*)d_in[31];
    const float* n3W2=(const float*)d_in[32], *n3b2=(const float*)d_in[33];
    const float* n3W3=(const float*)d_in[34], *n3b3=(const float*)d_in[35];

    const int N = in_sizes[0] / 12;      // 16384
    float* ws = (float*)d_ws;
    size_t off = 0;
    auto alloc = [&](size_t cnt){ float* p = ws + off; off += cnt; return p; };
    float* padw = alloc(PAD_TOTAL);
    _Float16* wt16 = (_Float16*)alloc((T_TOTAL+1)/2 + 8);
    float* x12  = alloc((size_t)N*12);
    _Float16* SA16 = (_Float16*)alloc((size_t)N*16);
    _Float16* SB16 = (_Float16*)alloc((size_t)N*20);
    float* h    = alloc((size_t)N*32);
    unsigned* part = (unsigned*)alloc((size_t)N*256);
    int*   idxb = (int*)alloc((size_t)N*KNN);
    float* wb   = alloc((size_t)N*KNN);
    float* xg   = alloc((size_t)N*64);
    (void)ws_size; (void)n_in; (void)out_size;

    float* outF = (float*)d_out;
    const int GB = N / 64;               // 256 blocks

    pad_all<<<(PAD_TOTAL+T_TOTAL+255)/256,256,0,stream>>>(gWs,gWh,n1W2,n2W3,n3W3,
                                                          n2W0,n2W1,n2W2,n3W0,n3W1,n3W2,
                                                          padw, wt16);
    f1_encoder<<<GB,512,0,stream>>>(x0, padw, n1W0,n1b0, n1W1,n1b1, n1b2,
                                    gbs, gbh, x12, SA16, SB16, h);
    knn_scan<<<(N/64)*2, 1024, 0, stream>>>(SA16, SB16, part, N);
    knn_merge<<<N/8, 512, 0, stream>>>(part, idxb, wb,
                                       ygenid, ygen, ycandid, ycand, outF, N);
    f2_agg<<<GB,512,0,stream>>>(h, idxb, wb, x12, gWo, gbo, xg);
    f345<<<GB,1024,0,stream>>>(xg, idxb, wb, c2Wrel, c2brel, c2Wroot, x0, padw, wt16,
                               n2b0,n2b1,n2b2,n2b3, n3b0,n3b1,n3b2,n3b3,
                               outF, outF + (size_t)N*6);
}

// Round 20
// 199.215 us; speedup vs baseline: 1.0540x; 1.0032x over previous
//
#include <hip/hip_runtime.h>
#include <math.h>

static constexpr int KNN = 40;

__device__ __forceinline__ float lrelu_f(float v){ return v >= 0.f ? v : 0.5f*v; }

typedef _Float16 half8 __attribute__((ext_vector_type(8)));
typedef float    f32x4 __attribute__((ext_vector_type(4)));

__device__ __forceinline__ void gload16(const void* g, void* l){
    __builtin_amdgcn_global_load_lds((const __attribute__((address_space(1))) void*)g,
                                     (__attribute__((address_space(3))) void*)l, 16, 0, 0);
}

// ---- fp32 padded-weight offsets (floats) ----
#define PAD_OFF_GWS   0
#define PAD_OFF_GWH   192
#define PAD_OFF_N1W2  576
#define PAD_OFF_N2W3  1600
#define PAD_OFF_N3W3  3616
#define PAD_TOTAL     5632

// ---- fp16 transposed weight offsets (halves): WT[n][k], n padded to 128 ----
#define T_N2W0  0
#define T_N2W1  8192
#define T_N2W2  24576
#define T_N3W0  40960
#define T_N3W1  53248
#define T_N3W2  69632
#define T_TOTAL 86016

__global__ void pad_all(const float* gWs,const float* gWh,const float* n1W2,
                        const float* n2W3,const float* n3W3,
                        const float* n2W0,const float* n2W1,const float* n2W2,
                        const float* n3W0,const float* n3W1,const float* n3W2,
                        float* __restrict__ wp, _Float16* __restrict__ wt)
{
    int i = blockIdx.x*blockDim.x + threadIdx.x;
    if (i < PAD_TOTAL) {
        const float* src; int cols, sh, off;
        if      (i < PAD_OFF_GWH)  { src=gWs;  cols=8;  sh=4; off=PAD_OFF_GWS;  }
        else if (i < PAD_OFF_N1W2) { src=gWh;  cols=22; sh=5; off=PAD_OFF_GWH;  }
        else if (i < PAD_OFF_N2W3) { src=n1W2; cols=12; sh=4; off=PAD_OFF_N1W2; }
        else if (i < PAD_OFF_N3W3) { src=n2W3; cols=6;  sh=4; off=PAD_OFF_N2W3; }
        else                       { src=n3W3; cols=6;  sh=4; off=PAD_OFF_N3W3; }
        int li = i - off;
        int r = li >> sh, c = li & ((1<<sh)-1);
        wp[i] = (c < cols) ? src[r*cols + c] : 0.f;
        return;
    }
    int j = i - PAD_TOTAL;
    if (j >= T_TOTAL) return;
    const float* src; int KP, K, off;
    if      (j < T_N2W1) { src=n2W0; KP=64;  K=64;  off=T_N2W0; }
    else if (j < T_N2W2) { src=n2W1; KP=128; K=126; off=T_N2W1; }
    else if (j < T_N3W0) { src=n2W2; KP=128; K=126; off=T_N2W2; }
    else if (j < T_N3W1) { src=n3W0; KP=96;  K=82;  off=T_N3W0; }
    else if (j < T_N3W2) { src=n3W1; KP=128; K=126; off=T_N3W1; }
    else                 { src=n3W2; KP=128; K=126; off=T_N3W2; }
    int li = j - off;
    int n = li / KP, k = li - n*KP;
    float v = (n < 126 && k < K) ? src[k*126 + n] : 0.f;
    wt[j] = (_Float16)v;
}

// ---- lin8: wave owns 8 output cols -> wave-uniform W addresses (64 rows) ----
template<int K, int NOUT, int WPITCH, bool RELU, int NTH>
__device__ __forceinline__
void lin8(const float* __restrict__ Xs, int xpitch,
          const float* __restrict__ W, const float* __restrict__ Bv,
          float* __restrict__ Y, int ypitch, int tid)
{
    constexpr int NP  = ((NOUT+7)/8)*8;
    constexpr int NCG = NP/8;
    constexpr int NW  = NTH/64;
    const int lane = tid & 63;
    for (int g0 = tid >> 6; g0 < NCG; g0 += NW) {
        const int cg = __builtin_amdgcn_readfirstlane(g0);
        float acc[8];
        #pragma unroll
        for (int j=0;j<8;++j){ int c=cg*8+j; acc[j] = (c < NOUT) ? Bv[c] : 0.f; }
        const float* xrow = &Xs[(long)lane*xpitch];
        const float* wp = &W[cg*8];
        #pragma unroll 4
        for (int k=0;k<K;++k){
            const float xv = xrow[k];
            const float4* w4 = reinterpret_cast<const float4*>(wp + (long)k*WPITCH);
            float4 a = w4[0], b = w4[1];
            acc[0]=fmaf(xv,a.x,acc[0]); acc[1]=fmaf(xv,a.y,acc[1]);
            acc[2]=fmaf(xv,a.z,acc[2]); acc[3]=fmaf(xv,a.w,acc[3]);
            acc[4]=fmaf(xv,b.x,acc[4]); acc[5]=fmaf(xv,b.y,acc[5]);
            acc[6]=fmaf(xv,b.z,acc[6]); acc[7]=fmaf(xv,b.w,acc[7]);
        }
        #pragma unroll
        for (int j=0;j<8;++j){
            int c = cg*8 + j;
            if (c < NOUT){ float v = acc[j]; if (RELU) v = lrelu_f(v); Y[(long)lane*ypitch + c] = v; }
        }
    }
    __syncthreads();
}

template<int K, int NOUT, int WPITCH, int NTH>
__device__ __forceinline__
void lin8_dual(const float* __restrict__ Xs, int xp, const float* __restrict__ X2s, int xp2,
               const float* __restrict__ W, const float* __restrict__ Bv, const float* __restrict__ W2,
               float* __restrict__ Y, int ypitch, int tid)
{
    constexpr int NP  = ((NOUT+7)/8)*8;
    constexpr int NCG = NP/8;
    constexpr int NW  = NTH/64;
    const int lane = tid & 63;
    for (int g0 = tid >> 6; g0 < NCG; g0 += NW) {
        const int cg = __builtin_amdgcn_readfirstlane(g0);
        float acc[8];
        #pragma unroll
        for (int j=0;j<8;++j){ int c=cg*8+j; acc[j] = (c < NOUT) ? Bv[c] : 0.f; }
        {
            const float* xrow = &Xs[(long)lane*xp];
            const float* wp = &W[cg*8];
            #pragma unroll 4
            for (int k=0;k<K;++k){
                const float xv = xrow[k];
                const float4* w4 = reinterpret_cast<const float4*>(wp + (long)k*WPITCH);
                float4 a = w4[0], b = w4[1];
                acc[0]=fmaf(xv,a.x,acc[0]); acc[1]=fmaf(xv,a.y,acc[1]);
                acc[2]=fmaf(xv,a.z,acc[2]); acc[3]=fmaf(xv,a.w,acc[3]);
                acc[4]=fmaf(xv,b.x,acc[4]); acc[5]=fmaf(xv,b.y,acc[5]);
                acc[6]=fmaf(xv,b.z,acc[6]); acc[7]=fmaf(xv,b.w,acc[7]);
            }
        }
        {
            const float* xrow = &X2s[(long)lane*xp2];
            const float* wp = &W2[cg*8];
            #pragma unroll 4
            for (int k=0;k<K;++k){
                const float xv = xrow[k];
                const float4* w4 = reinterpret_cast<const float4*>(wp + (long)k*WPITCH);
                float4 a = w4[0], b = w4[1];
                acc[0]=fmaf(xv,a.x,acc[0]); acc[1]=fmaf(xv,a.y,acc[1]);
                acc[2]=fmaf(xv,a.z,acc[2]); acc[3]=fmaf(xv,a.w,acc[3]);
                acc[4]=fmaf(xv,b.x,acc[4]); acc[5]=fmaf(xv,b.y,acc[5]);
                acc[6]=fmaf(xv,b.z,acc[6]); acc[7]=fmaf(xv,b.w,acc[7]);
            }
        }
        #pragma unroll
        for (int j=0;j<8;++j){
            int c = cg*8 + j;
            if (c < NOUT) Y[(long)lane*ypitch + c] = acc[j];
        }
    }
    __syncthreads();
}

// ---------------- F1: nn1 encoder + gWs + gWh + SA/SB build (512 thr) ----------------
__global__ __launch_bounds__(512)
void f1_encoder(const float* __restrict__ x0, const float* __restrict__ wp,
                const float* n1W0,const float* n1b0,const float* n1W1,const float* n1b1,
                const float* n1b2, const float* gbs, const float* gbh,
                float* __restrict__ x12g,
                _Float16* __restrict__ SA16, _Float16* __restrict__ SB16 /*pitch 40*/,
                float* __restrict__ hg /*pitch 32*/)
{
    __shared__ float A1[64*65], A2[64*65], Ss[64*9];
    const int tid = threadIdx.x;
    const long row0 = (long)blockIdx.x*64;
    lin8<12,64,64,true,512>(x0+row0*12,12, n1W0, n1b0, A1,65, tid);
    lin8<64,64,64,true,512>(A1,65, n1W1, n1b1, A2,65, tid);
    lin8<64,12,16,true,512>(A2,65, wp+PAD_OFF_N1W2, n1b2, A1,13, tid);
    for (int i=tid;i<64*12;i+=512){ int r=i/12,c=i-r*12; x12g[(row0+r)*12+c]=A1[r*13+c]; }
    lin8<12,8,16,false,512>(A1,13, wp+PAD_OFF_GWS, gbs, Ss,9, tid);
    lin8<12,22,32,false,512>(A1,13, wp+PAD_OFF_GWH, gbh, hg+row0*32,32, tid);
    if (tid < 64) {
        const long node = row0 + tid;
        float sv[8]; float nq = 0.f;
        #pragma unroll
        for (int k=0;k<8;++k){ float v=Ss[tid*9+k]; sv[k]=v; nq=fmaf(v,v,nq); }
        _Float16 ch[8], clo[8];
        #pragma unroll
        for (int k=0;k<8;++k){ ch[k]=(_Float16)sv[k]; clo[k]=(_Float16)(sv[k]-(float)ch[k]); }
        _Float16 nh = (_Float16)nq, nl = (_Float16)(nq-(float)nh);
        const _Float16 one = (_Float16)1.f, zero = (_Float16)0.f;
        half8 a0,a1,a2,b0,b2;
        #pragma unroll
        for (int k=0;k<8;++k){
            a0[k]=ch[k]; a1[k]=clo[k]; a2[k]=ch[k];
            b0[k]=(_Float16)(-2.f*(float)ch[k]);
            b2[k]=(_Float16)(-2.f*(float)clo[k]);
        }
        half8 a3 = {nh, nl, one, one, zero, zero, zero, zero};
        half8 b3 = {one, one, nh, nl, zero, zero, zero, zero};
        half8* ap = (half8*)&SA16[(size_t)node*32];
        ap[0]=a0; ap[1]=a1; ap[2]=a2; ap[3]=a3;
        half8* bp = (half8*)&SB16[(size_t)node*40];
        bp[0]=b0; bp[1]=b0; bp[2]=b2; bp[3]=b3;
        bp[4]=half8{zero,zero,zero,zero,zero,zero,zero,zero};
    }
}

// ---------------- kNN scan: 64 queries/block, 16 waves ----------------
template<int C>
__device__ __forceinline__ unsigned dpp_umin(unsigned x){
    unsigned y = (unsigned)__builtin_amdgcn_update_dpp((int)x, (int)x, C, 0xf, 0xf, false);
    return x < y ? x : y;
}
__device__ __forceinline__ unsigned wave_umin64(unsigned x){
    x = dpp_umin<0x111>(x);
    x = dpp_umin<0x112>(x);
    x = dpp_umin<0x114>(x);
    x = dpp_umin<0x118>(x);
    x = dpp_umin<0x142>(x);
    x = dpp_umin<0x143>(x);
    return x;
}
__device__ __forceinline__ unsigned med3_u32(unsigned a, unsigned b, unsigned c){
    unsigned d;
    asm("v_med3_u32 %0, %1, %2, %3" : "=v"(d) : "v"(a), "v"(b), "v"(c));
    return d;
}

__global__ __launch_bounds__(1024)
void knn_scan(const _Float16* __restrict__ SA, const _Float16* __restrict__ SB,
              unsigned* __restrict__ part, int N)
{
    __shared__ __align__(16) _Float16 SBl[2][256*40];
    const int tid  = threadIdx.x;
    const int lane = tid & 63;
    const int w    = tid >> 6;
    const int g    = w >> 2, qt = w & 3;
    const int col  = lane & 15, kg = lane >> 4;
    const int qg   = blockIdx.x >> 1, half = blockIdx.x & 1;
    const int qb   = qg*64 + g*16;
    const int qtile = qb >> 8;
    const int rhs0  = (qb & 255) + kg*4;
    const int T0 = half*32;

    half8 afrag = *(const half8*)&SA[(size_t)(qb + col)*32 + kg*8];
    unsigned s0[4], s1[4];
    #pragma unroll
    for (int r=0;r<4;++r){ s0[r]=0xFFFFFFFFu; s1[r]=0xFFFFFFFFu; }

    {
        const char* gp = (const char*)(SB + (size_t)T0*256*40);
        gload16(gp + (size_t)tid*16, &SBl[0][(size_t)tid*8]);
        if (tid < 256) gload16(gp + (size_t)(tid+1024)*16, &SBl[0][(size_t)(tid+1024)*8]);
    }
    __syncthreads();
    #pragma unroll 1
    for (int t = T0; t < T0+32; ++t) {
        const int cur = t & 1;
        if (t+1 < T0+32) {
            const char* gp = (const char*)(SB + (size_t)(t+1)*256*40);
            _Float16* lp = SBl[cur^1];
            gload16(gp + (size_t)tid*16, &lp[(size_t)tid*8]);
            if (tid < 256) gload16(gp + (size_t)(tid+1024)*16, &lp[(size_t)(tid+1024)*8]);
        }
        const _Float16* tb = SBl[cur];
        if (t != qtile) {
            #pragma unroll
            for (int c3=0;c3<4;++c3){
                const int cl_ = (qt*4+c3)*16 + col;
                half8 b = *(const half8*)&tb[cl_*40 + kg*8];
                f32x4 acc = {0.f,0.f,0.f,0.f};
                acc = __builtin_amdgcn_mfma_f32_16x16x32_f16(afrag, b, acc, 0, 0, 0);
                const unsigned ib = (unsigned)((t<<8)|cl_);
                #pragma unroll
                for (int r=0;r<4;++r){
                    float d2 = fmaxf(acc[r], 0.f);
                    unsigned key = (__float_as_uint(d2) & 0xFFFFC000u) | ib;
                    unsigned lo = s0[r] < key ? s0[r] : key;
                    s1[r] = med3_u32(s0[r], s1[r], key);
                    s0[r] = lo;
                }
            }
        } else {
            #pragma unroll
            for (int c3=0;c3<4;++c3){
                const int cl_ = (qt*4+c3)*16 + col;
                half8 b = *(const half8*)&tb[cl_*40 + kg*8];
                f32x4 acc = {0.f,0.f,0.f,0.f};
                acc = __builtin_amdgcn_mfma_f32_16x16x32_f16(afrag, b, acc, 0, 0, 0);
                const unsigned ib = (unsigned)((t<<8)|cl_);
                #pragma unroll
                for (int r=0;r<4;++r){
                    float d2 = fmaxf(acc[r], 0.f);
                    unsigned key = (__float_as_uint(d2) & 0xFFFFC000u) | ib;
                    if (cl_ == rhs0 + r) key = 0xFFFFFFFFu;
                    unsigned lo = s0[r] < key ? s0[r] : key;
                    s1[r] = med3_u32(s0[r], s1[r], key);
                    s0[r] = lo;
                }
            }
        }
        __syncthreads();
    }

    #pragma unroll
    for (int r=0;r<4;++r){
        const long q = (long)qg*64 + g*16 + kg*4 + r;
        unsigned* pp = &part[((size_t)q*2 + half)*128 + qt*32 + col*2];
        pp[0] = s0[r]; pp[1] = s1[r];
    }
}

// ---------------- kNN merge + passthrough copyout ----------------
__global__ __launch_bounds__(512)
void knn_merge(const unsigned* __restrict__ part,
               int* __restrict__ idx_out, float* __restrict__ w_out,
               const int* __restrict__ gid, const float* __restrict__ gy,
               const int* __restrict__ cid, const float* __restrict__ cy,
               float* __restrict__ out, int N)
{
    const int lane = threadIdx.x & 63, w = threadIdx.x >> 6;
    const long q = (long)blockIdx.x*8 + w;
    const uint4 kk = *reinterpret_cast<const uint4*>(&part[(size_t)q*256 + lane*4]);
    unsigned k0=kk.x, k1=kk.y, k2=kk.z, k3=kk.w;
    unsigned saved = 0;
    #pragma unroll 1
    for (int p=0;p<KNN;++p){
        unsigned a = k0 < k1 ? k0 : k1;
        unsigned b = k2 < k3 ? k2 : k3;
        unsigned lmin = a < b ? a : b;
        unsigned red = wave_umin64(lmin);
        unsigned gm = (unsigned)__builtin_amdgcn_readlane((int)red, 63);
        unsigned long long bal = __ballot(lmin == gm);
        int owner = __ffsll((long long)bal) - 1;
        if (lane == owner){
            if      (k0 == gm) k0 = 0xFFFFFFFFu;
            else if (k1 == gm) k1 = 0xFFFFFFFFu;
            else if (k2 == gm) k2 = 0xFFFFFFFFu;
            else               k3 = 0xFFFFFFFFu;
        }
        if (lane == p) saved = gm;
    }
    if (lane < KNN){
        idx_out[q*KNN + lane] = (int)(saved & 16383u);
        const float d2 = __uint_as_float(saved & 0xFFFFC000u);
        w_out[q*KNN + lane] = expf(-10.f*d2);
    }
    // ---- passthrough outputs ----
    long i = (long)blockIdx.x*blockDim.x + threadIdx.x;
    long n = N;
    if (i < n)            out[12*n + i]         = (float)gid[i];
    else if (i < 7*n)     out[13*n + (i - n)]   = gy[i - n];
    else if (i < 8*n)     out[19*n + (i - 7*n)] = (float)cid[i - 7*n];
    else if (i < 14*n)    out[20*n + (i - 8*n)] = cy[i - 8*n];
}

// ---------------- F2: GravNet aggregate + lin 56->64 (512 thr) ----------------
__global__ __launch_bounds__(512)
void f2_agg(const float* __restrict__ hg /*pitch 32*/, const int* __restrict__ idx,
            const float* __restrict__ wgt, const float* __restrict__ x12g,
            const float* gWo, const float* gbo, float* __restrict__ xg)
{
    __shared__ int   IDs[64*40];
    __shared__ float Wt[64*40];
    __shared__ float AGG[64*57];
    const int tid = threadIdx.x;
    const long row0 = (long)blockIdx.x*64;
    for (int i=tid;i<64*40;i+=512){ int r=i/40,k=i-r*40;
        IDs[i]=idx[(row0+r)*40+k]; Wt[i]=wgt[(row0+r)*40+k]; }
    for (int i=tid;i<64*12;i+=512){ int r=i/12,c=i-r*12; AGG[r*57+44+c]=x12g[(row0+r)*12+c]; }
    __syncthreads();
    {
        const int r = tid & 63, g = tid >> 6;
        const int f0 = g*4;
        const int nf = (f0 < 22) ? ((22-f0) < 4 ? (22-f0) : 4) : 0;
        float sm[4], mx[4];
        #pragma unroll
        for (int u=0;u<4;++u){ sm[u]=0.f; mx[u]=-INFINITY; }
        if (nf > 0) {
            #pragma unroll 1
            for (int k=0;k<40;++k){
                int j = IDs[r*40+k]; float wv = Wt[r*40+k];
                float4 h0 = *reinterpret_cast<const float4*>(&hg[(long)j*32 + f0]);
                float hv[4] = {h0.x,h0.y,h0.z,h0.w};
                #pragma unroll
                for (int u=0;u<4;++u){ float m = hv[u]*wv; sm[u]+=m; mx[u]=fmaxf(mx[u],m); }
            }
            #pragma unroll
            for (int u=0;u<4;++u) if (u<nf){ AGG[r*57+f0+u]=sm[u]*(1.f/40.f); AGG[r*57+22+f0+u]=mx[u]; }
        }
    }
    __syncthreads();
    lin8<56,64,64,false,512>(AGG,57, gWo, gbo, xg+row0*64,64, tid);
}

// ---------------- F345: GraphConv + nn2 + nn3 fused (64 rows, 1024 thr) ----------------
// mfma_layer with HALF-STAGED weights: Wl holds 64 x KP halves (16KB max).
// Pass A: stage WT rows [0,64), compute col-tiles 0..3 (acc0).
// Pass B: stage WT rows [64,128), compute col-tiles 4..7 (acc1).
template<int KP>
__device__ __forceinline__
void mfma_layer(const _Float16* __restrict__ Xl, const _Float16* __restrict__ WTg,
                _Float16* __restrict__ Wl,
                const float* __restrict__ Bv, _Float16* __restrict__ Yl, int tid)
{
    const int lane = tid & 63;
    const int wid  = __builtin_amdgcn_readfirstlane(tid >> 6);
    const int m   = wid & 3;
    const int nb  = wid >> 2;
    const int c15 = lane & 15;
    const int kg  = lane >> 4;
    const _Float16* xb = &Xl[(m*16 + c15)*136];
    const _Float16* wl = &Wl[(nb*16 + c15)*KP];
    constexpr int CHUNKS = 64*KP/8;

    // ---- half 0: cols 0..63 ----
    {
        const half8* src = reinterpret_cast<const half8*>(WTg);
        half8* dst = reinterpret_cast<half8*>(Wl);
        #pragma unroll
        for (int i = tid; i < CHUNKS; i += 1024) dst[i] = src[i];
    }
    __syncthreads();
    f32x4 acc0 = {0.f,0.f,0.f,0.f};
    #pragma unroll
    for (int ks = 0; ks < KP/32; ++ks) {
        const int kb = kg*8 + ks*32;
        half8 a  = *reinterpret_cast<const half8*>(&xb[kb]);
        half8 b0 = *reinterpret_cast<const half8*>(&wl[kb]);
        acc0 = __builtin_amdgcn_mfma_f32_16x16x32_f16(a, b0, acc0, 0, 0, 0);
    }
    {
        const int drow = m*16 + kg*4;
        const int c0 = nb*16 + c15;
        #pragma unroll
        for (int r = 0; r < 4; ++r) {
            float v0 = lrelu_f(acc0[r] + Bv[c0]);
            Yl[(drow+r)*136 + c0] = (_Float16)v0;
        }
    }
    __syncthreads();
    // ---- half 1: cols 64..127 ----
    {
        const half8* src = reinterpret_cast<const half8*>(WTg + 64*KP);
        half8* dst = reinterpret_cast<half8*>(Wl);
        #pragma unroll
        for (int i = tid; i < CHUNKS; i += 1024) dst[i] = src[i];
    }
    __syncthreads();
    f32x4 acc1 = {0.f,0.f,0.f,0.f};
    #pragma unroll
    for (int ks = 0; ks < KP/32; ++ks) {
        const int kb = kg*8 + ks*32;
        half8 a  = *reinterpret_cast<const half8*>(&xb[kb]);
        half8 b1 = *reinterpret_cast<const half8*>(&wl[kb]);
        acc1 = __builtin_amdgcn_mfma_f32_16x16x32_f16(a, b1, acc1, 0, 0, 0);
    }
    {
        const int drow = m*16 + kg*4;
        const int c1 = (nb+4)*16 + c15;
        #pragma unroll
        for (int r = 0; r < 4; ++r) {
            float v1 = (c1 < 126) ? lrelu_f(acc1[r] + Bv[c1]) : 0.f;
            Yl[(drow+r)*136 + c1] = (_Float16)v1;
        }
    }
    __syncthreads();
}

__device__ __forceinline__
void lin_out6h(const _Float16* __restrict__ Xs, const float* __restrict__ Wp,
               float* __restrict__ Wl6, const float* __restrict__ Bv,
               float* __restrict__ Y, int ypitch, int tid)
{
    for (int i = tid; i < 126*8; i += 1024) {
        int k = i >> 3, c = i & 7;
        Wl6[i] = Wp[k*16 + c];
    }
    __syncthreads();
    if (tid < 64*6) {
        const int r = tid / 6, c = tid - r*6;
        float acc = Bv[c];
        const _Float16* xrow = &Xs[r*136];
        #pragma unroll 4
        for (int k=0;k<126;++k) acc = fmaf((float)xrow[k], Wl6[k*8+c], acc);
        Y[(long)r*ypitch + c] = lrelu_f(acc);
    }
    __syncthreads();
}

__global__ __launch_bounds__(1024)
void f345(const float* __restrict__ xgin, const int* __restrict__ idx,
          const float* __restrict__ wgt,
          const float* c2Wrel, const float* c2brel, const float* c2Wroot,
          const float* __restrict__ x0,
          const float* __restrict__ wp, const _Float16* __restrict__ wt,
          const float* A_b0,const float* A_b1,const float* A_b2,const float* A_b3,
          const float* B_b0,const float* B_b1,const float* B_b2,const float* B_b3,
          float* __restrict__ outIds, float* __restrict__ outP4)
{
    __shared__ float XCs[64*65];                      // 16640 B persistent
    __shared__ __align__(16) char uni[53760];         // phase-union scratch
    // f3 view
    int*   IDs = (int*)uni;                           // 10240 B
    float* Wt  = (float*)(uni+10240);                 // 10240 B
    float* NB  = (float*)(uni+20480);                 // 16640 B
    float* XGs = (float*)(uni+37120);                 // 16640 B
    // f45 view
    _Float16* bufA = (_Float16*)uni;                  // 17408 B
    _Float16* bufB = (_Float16*)(uni+17408);          // 17408 B
    _Float16* Wl   = (_Float16*)(uni+34816);          // 16384 B (64 x 128 halves max)
    float*    IDS6 = (float*)(uni+51200);             // 1536 B

    const int tid = threadIdx.x;
    const long row0 = (long)blockIdx.x*64;
    for (int i=tid;i<64*40;i+=1024){ int r=i/40,k=i-r*40;
        IDs[i]=idx[(row0+r)*40+k]; Wt[i]=wgt[(row0+r)*40+k]; }
    for (int i=tid;i<64*64;i+=1024){ int r=i>>6,c=i&63; XGs[r*65+c]=xgin[(row0+r)*64+c]; }
    __syncthreads();
    {
        const int r = tid & 63, g = tid >> 6;
        float acc[4] = {0.f,0.f,0.f,0.f};
        #pragma unroll 1
        for (int k=0;k<40;++k){
            int j = IDs[r*40+k]; float wv = Wt[r*40+k];
            float4 v = *reinterpret_cast<const float4*>(&xgin[(long)j*64 + g*4]);
            acc[0]=fmaf(v.x,wv,acc[0]); acc[1]=fmaf(v.y,wv,acc[1]);
            acc[2]=fmaf(v.z,wv,acc[2]); acc[3]=fmaf(v.w,wv,acc[3]);
        }
        __syncthreads();
        #pragma unroll
        for (int j=0;j<4;++j) NB[r*65 + g*4 + j] = acc[j];
    }
    __syncthreads();
    lin8_dual<64,64,64,1024>(NB,65, XGs,65, c2Wrel,c2brel,c2Wroot, XCs,65, tid);
    for (int i=tid;i<64*64;i+=1024){ int r=i>>6,c=i&63;
        bufA[r*136+c] = (_Float16)XCs[r*65+c]; }
    __syncthreads();
    mfma_layer<64>(bufA, wt+T_N2W0, Wl, A_b0, bufB, tid);
    mfma_layer<128>(bufB, wt+T_N2W1, Wl, A_b1, bufA, tid);
    mfma_layer<128>(bufA, wt+T_N2W2, Wl, A_b2, bufB, tid);
    lin_out6h(bufB, wp+PAD_OFF_N2W3, (float*)Wl, A_b3, IDS6, 6, tid);
    for (int i=tid;i<64*6;i+=1024){ int r=i/6,c=i-r*6; outIds[(row0+r)*6+c]=IDS6[i]; }
    for (int i=tid;i<64*96;i+=1024){
        int r=i/96, c=i-r*96;
        float v;
        if (c < 64)      v = XCs[r*65 + c];
        else if (c < 70) v = IDS6[r*6 + (c-64)];
        else if (c < 82) v = x0[(row0+r)*12 + (c-70)];
        else             v = 0.f;
        bufA[r*136+c] = (_Float16)v;
    }
    __syncthreads();
    mfma_layer<96>(bufA, wt+T_N3W0, Wl, B_b0, bufB, tid);
    mfma_layer<128>(bufB, wt+T_N3W1, Wl, B_b1, bufA, tid);
    mfma_layer<128>(bufA, wt+T_N3W2, Wl, B_b2, bufB, tid);
    lin_out6h(bufB, wp+PAD_OFF_N3W3, (float*)Wl, B_b3, outP4+row0*6, 6, tid);
}

extern "C" void kernel_launch(void* const* d_in, const int* in_sizes, int n_in,
                              void* d_out, int out_size, void* d_ws, size_t ws_size,
                              hipStream_t stream)
{
    const float* x0     = (const float*)d_in[0];
    const float* ygen   = (const float*)d_in[1];
    const float* ycand  = (const float*)d_in[2];
    const int*   ygenid = (const int*)d_in[3];
    const int*   ycandid= (const int*)d_in[4];
    const float* n1W0=(const float*)d_in[5],  *n1b0=(const float*)d_in[6];
    const float* n1W1=(const float*)d_in[7],  *n1b1=(const float*)d_in[8];
    const float* n1W2=(const float*)d_in[9],  *n1b2=(const float*)d_in[10];
    const float* gWs =(const float*)d_in[11], *gbs =(const float*)d_in[12];
    const float* gWh =(const float*)d_in[13], *gbh =(const float*)d_in[14];
    const float* gWo =(const float*)d_in[15], *gbo =(const float*)d_in[16];
    const float* c2Wrel=(const float*)d_in[17], *c2brel=(const float*)d_in[18];
    const float* c2Wroot=(const float*)d_in[19];
    const float* n2W0=(const float*)d_in[20], *n2b0=(const float*)d_in[21];
    const float* n2W1=(const float*)d_in[22], *n2b1=(const float*)d_in[23];
    const float* n2W2=(const float*)d_in[24], *n2b2=(const float*)d_in[25];
    const float* n2W3=(const float*)d_in[26], *n2b3=(const float*)d_in[27];
    const float* n3W0=(const float*)d_in[28], *n3b0=(const float*)d_in[29];
    const float* n3W1=(const float*)d_in[30], *n3b1=(const float*)d_in[31];
    const float* n3W2=(const float*)d_in[32], *n3b2=(const float*)d_in[33];
    const float* n3W3=(const float*)d_in[34], *n3b3=(const float*)d_in[35];

    const int N = in_sizes[0] / 12;      // 16384
    float* ws = (float*)d_ws;
    size_t off = 0;
    auto alloc = [&](size_t cnt){ float* p = ws + off; off += cnt; return p; };
    float* padw = alloc(PAD_TOTAL);
    _Float16* wt16 = (_Float16*)alloc((T_TOTAL+1)/2 + 8);
    float* x12  = alloc((size_t)N*12);
    _Float16* SA16 = (_Float16*)alloc((size_t)N*16);
    _Float16* SB16 = (_Float16*)alloc((size_t)N*20);
    float* h    = alloc((size_t)N*32);
    unsigned* part = (unsigned*)alloc((size_t)N*256);
    int*   idxb = (int*)alloc((size_t)N*KNN);
    float* wb   = alloc((size_t)N*KNN);
    float* xg   = alloc((size_t)N*64);
    (void)ws_size; (void)n_in; (void)out_size;

    float* outF = (float*)d_out;
    const int GB = N / 64;               // 256 blocks

    pad_all<<<(PAD_TOTAL+T_TOTAL+255)/256,256,0,stream>>>(gWs,gWh,n1W2,n2W3,n3W3,
                                                          n2W0,n2W1,n2W2,n3W0,n3W1,n3W2,
                                                          padw, wt16);
    f1_encoder<<<GB,512,0,stream>>>(x0, padw, n1W0,n1b0, n1W1,n1b1, n1b2,
                                    gbs, gbh, x12, SA16, SB16, h);
    knn_scan<<<(N/64)*2, 1024, 0, stream>>>(SA16, SB16, part, N);
    knn_merge<<<N/8, 512, 0, stream>>>(part, idxb, wb,
                                       ygenid, ygen, ycandid, ycand, outF, N);
    f2_agg<<<GB,512,0,stream>>>(h, idxb, wb, x12, gWo, gbo, xg);
    f345<<<GB,1024,0,stream>>>(xg, idxb, wb, c2Wrel, c2brel, c2Wroot, x0, padw, wt16,
                               n2b0,n2b1,n2b2,n2b3, n3b0,n3b1,n3b2,n3b3,
                               outF, outF + (size_t)N*6);
}